// Round 1
// baseline (3236.855 us; speedup 1.0000x reference)
//
#include <hip/hip_runtime.h>
#include <math.h>

#define NN 10000
#define NE 160000
#define H  128
#define LD 8

__device__ __forceinline__ float silu_f(float x){ return x / (1.0f + expf(-x)); }

__device__ __forceinline__ float4 f4z(){ return make_float4(0.f,0.f,0.f,0.f); }

__device__ __forceinline__ void fma4(float4& acc, float s, const float4 w){
    acc.x = fmaf(s, w.x, acc.x);
    acc.y = fmaf(s, w.y, acc.y);
    acc.z = fmaf(s, w.z, acc.z);
    acc.w = fmaf(s, w.w, acc.w);
}

__device__ __forceinline__ float4 silu4(float4 a, float4 b){
    return make_float4(silu_f(a.x+b.x), silu_f(a.y+b.y), silu_f(a.z+b.z), silu_f(a.w+b.w));
}

// ---------------------------------------------------------------------------
// K1: per-node: LayerNorm -> x; q,k,v; vec = vf*vln_w; vec123 -> vec_dot,vec3;
//     Vt = vec@Wtrg; Vs = vec@Wsrc.
// block = 128 threads (one node per block), thread h owns output column h.
// Weight columns read from global (L2-resident); x/vec rows broadcast from LDS.
// ---------------------------------------------------------------------------
__global__ __launch_bounds__(128) void node_pre(
    const float* __restrict__ nf, const float* __restrict__ vf,
    const float* __restrict__ ln_s, const float* __restrict__ ln_b,
    const float* __restrict__ vlnw, const float* __restrict__ W_vec,
    const float* __restrict__ Wq, const float* __restrict__ bq,
    const float* __restrict__ Wk, const float* __restrict__ bk,
    const float* __restrict__ Wv, const float* __restrict__ bv,
    const float* __restrict__ Wtrg, const float* __restrict__ Wsrc,
    float* __restrict__ q, float* __restrict__ k, float* __restrict__ v,
    float* __restrict__ vec, float* __restrict__ vdot, float* __restrict__ vec3,
    float* __restrict__ Vt, float* __restrict__ Vs)
{
    const int n = blockIdx.x;
    const int h = threadIdx.x;
    __shared__ float x_s[H];
    __shared__ float vec_s[LD][H];
    __shared__ float red[4];

    float xv = nf[(size_t)n*H + h];
    float s1 = xv, s2 = xv*xv;
    #pragma unroll
    for (int o = 32; o >= 1; o >>= 1){
        s1 += __shfl_xor(s1, o, 64);
        s2 += __shfl_xor(s2, o, 64);
    }
    const int wid = h >> 6;
    if ((h & 63) == 0){ red[wid] = s1; red[2+wid] = s2; }
    __syncthreads();
    float mean = (red[0] + red[1]) * (1.0f/H);
    float var  = (red[2] + red[3]) * (1.0f/H) - mean*mean;
    float x = (xv - mean) * rsqrtf(var + 1e-5f) * ln_s[h] + ln_b[h];
    x_s[h] = x;
    float w = vlnw[h];
    #pragma unroll
    for (int l = 0; l < LD; l++){
        size_t i = ((size_t)n*LD + l)*H + h;
        float t = vf[i] * w;
        vec_s[l][h] = t;
        vec[i] = t;
    }
    __syncthreads();

    float aq = bq[h], ak = bk[h], av = bv[h];
    float a1[LD], a2[LD], a3[LD], at[LD], as_[LD];
    #pragma unroll
    for (int l = 0; l < LD; l++){ a1[l]=0.f; a2[l]=0.f; a3[l]=0.f; at[l]=0.f; as_[l]=0.f; }

    for (int kk = 0; kk < H; kk++){
        float xk = x_s[kk];
        aq = fmaf(xk, Wq[kk*H + h], aq);
        ak = fmaf(xk, Wk[kk*H + h], ak);
        av = fmaf(xk, Wv[kk*H + h], av);
        float w1 = W_vec[kk*(3*H) + h];
        float w2 = W_vec[kk*(3*H) + H + h];
        float w3 = W_vec[kk*(3*H) + 2*H + h];
        float wt = Wtrg[kk*H + h];
        float ws = Wsrc[kk*H + h];
        #pragma unroll
        for (int l = 0; l < LD; l++){
            float vk = vec_s[l][kk];
            a1[l] = fmaf(vk, w1, a1[l]);
            a2[l] = fmaf(vk, w2, a2[l]);
            a3[l] = fmaf(vk, w3, a3[l]);
            at[l] = fmaf(vk, wt, at[l]);
            as_[l]= fmaf(vk, ws, as_[l]);
        }
    }
    q[(size_t)n*H + h] = aq;
    k[(size_t)n*H + h] = ak;
    v[(size_t)n*H + h] = av;
    float vd = 0.f;
    #pragma unroll
    for (int l = 0; l < LD; l++) vd = fmaf(a1[l], a2[l], vd);
    vdot[(size_t)n*H + h] = vd;
    #pragma unroll
    for (int l = 0; l < LD; l++){
        size_t i = ((size_t)n*LD + l)*H + h;
        vec3[i] = a3[l];
        Vt[i]   = at[l];
        Vs[i]   = as_[l];
    }
}

// ---------------------------------------------------------------------------
// K2: fused dk/dv GEMV + head attention + vj + node_agg atomic scatter.
// 32 edges per block, 256 threads: g=tid&31 owns cols [4g,4g+4); r0=tid>>5,
// rows r0+8j (j=0..3). Wdk+Wdv staged in LDS (128KB) + 32 edge rows (16KB).
// ---------------------------------------------------------------------------
__global__ __launch_bounds__(256) void edge_attn(
    const float* __restrict__ ef,
    const float* __restrict__ Wdk, const float* __restrict__ bdk,
    const float* __restrict__ Wdv, const float* __restrict__ bdv,
    const int* __restrict__ snd, const int* __restrict__ rcv,
    const float* __restrict__ dist,
    const float* __restrict__ q, const float* __restrict__ k, const float* __restrict__ v,
    float* __restrict__ vj, float* __restrict__ node_agg)
{
    __shared__ float wdk_s[H*H];
    __shared__ float wdv_s[H*H];
    __shared__ float e_s[32*H];
    __shared__ int   snd_s[32];
    __shared__ int   rcv_s[32];
    __shared__ float cut_s[32];

    const int tid = threadIdx.x;
    const size_t e0 = (size_t)blockIdx.x * 32;
    for (int i = tid; i < H*H/4; i += 256){
        ((float4*)wdk_s)[i] = ((const float4*)Wdk)[i];
        ((float4*)wdv_s)[i] = ((const float4*)Wdv)[i];
    }
    for (int i = tid; i < 32*H/4; i += 256)
        ((float4*)e_s)[i] = ((const float4*)(ef + e0*H))[i];
    if (tid < 32){
        snd_s[tid] = snd[e0 + tid];
        rcv_s[tid] = rcv[e0 + tid];
        float d = dist[e0 + tid];
        cut_s[tid] = (d < 5.0f) ? 0.5f*(cosf(d*0.6283185307179586f) + 1.0f) : 0.0f;
    }
    __syncthreads();

    const int g = tid & 31, r0 = tid >> 5;
    float4 adk[4], adv[4];
    #pragma unroll
    for (int j = 0; j < 4; j++){ adk[j] = f4z(); adv[j] = f4z(); }

    for (int kk = 0; kk < H; kk++){
        float4 wk4 = *(float4*)&wdk_s[kk*H + g*4];
        float4 wv4 = *(float4*)&wdv_s[kk*H + g*4];
        #pragma unroll
        for (int j = 0; j < 4; j++){
            float e = e_s[(r0 + 8*j)*H + kk];
            fma4(adk[j], e, wk4);
            fma4(adv[j], e, wv4);
        }
    }
    float4 bk4 = *(const float4*)&bdk[g*4];
    float4 bv4 = *(const float4*)&bdv[g*4];
    #pragma unroll
    for (int j = 0; j < 4; j++){
        adk[j] = silu4(adk[j], bk4);
        adv[j] = silu4(adv[j], bv4);
    }
    #pragma unroll
    for (int j = 0; j < 4; j++){
        int row = r0 + 8*j;
        int s = snd_s[row], r = rcv_s[row];
        float4 q4 = *(const float4*)&q[(size_t)r*H + g*4];
        float4 k4 = *(const float4*)&k[(size_t)s*H + g*4];
        float p = q4.x*k4.x*adk[j].x + q4.y*k4.y*adk[j].y
                + q4.z*k4.z*adk[j].z + q4.w*k4.w*adk[j].w;
        p += __shfl_xor(p, 1, 64);   // head = 16 cols = 4 adjacent g lanes
        p += __shfl_xor(p, 2, 64);
        float attn = silu_f(p) * cut_s[row];
        float4 v4 = *(const float4*)&v[(size_t)s*H + g*4];
        float4 o = make_float4(v4.x*adv[j].x*attn, v4.y*adv[j].y*attn,
                               v4.z*adv[j].z*attn, v4.w*adv[j].w*attn);
        *(float4*)&vj[(e0 + row)*H + g*4] = o;
        float* na = &node_agg[(size_t)r*H + g*4];
        atomicAdd(na+0, o.x); atomicAdd(na+1, o.y);
        atomicAdd(na+2, o.z); atomicAdd(na+3, o.w);
    }
}

// ---------------------------------------------------------------------------
// K3: s = silu(vj@Ws + bs) [E,2H] fused with vec_msg scatter into vec_agg.
// 16 edges per block, 256 threads; Ws (128KB) + vj rows (8KB) in LDS.
// ---------------------------------------------------------------------------
__global__ __launch_bounds__(256) void edge_s_scatter(
    const float* __restrict__ vj, const float* __restrict__ Ws, const float* __restrict__ bs,
    const int* __restrict__ snd, const int* __restrict__ rcv,
    const float* __restrict__ dij, const float* __restrict__ vec,
    float* __restrict__ vec_agg)
{
    __shared__ float ws_s[H*2*H];
    __shared__ float vj_s[16*H];
    __shared__ int   snd_s[16];
    __shared__ int   rcv_s[16];
    __shared__ float dij_s[16][LD];

    const int tid = threadIdx.x;
    const size_t e0 = (size_t)blockIdx.x * 16;
    for (int i = tid; i < H*2*H/4; i += 256)
        ((float4*)ws_s)[i] = ((const float4*)Ws)[i];
    for (int i = tid; i < 16*H/4; i += 256)
        ((float4*)vj_s)[i] = ((const float4*)(vj + e0*H))[i];
    if (tid < 16){ snd_s[tid] = snd[e0+tid]; rcv_s[tid] = rcv[e0+tid]; }
    if (tid < 16*LD) ((float*)dij_s)[tid] = dij[e0*LD + tid];
    __syncthreads();

    const int g = tid & 31, r0 = tid >> 5;
    float4 a1[2], a2[2];
    a1[0]=f4z(); a1[1]=f4z(); a2[0]=f4z(); a2[1]=f4z();

    for (int kk = 0; kk < H; kk++){
        float4 w1 = *(float4*)&ws_s[kk*2*H + g*4];
        float4 w2 = *(float4*)&ws_s[kk*2*H + H + g*4];
        float ea = vj_s[r0*H + kk];
        float eb = vj_s[(r0+8)*H + kk];
        fma4(a1[0], ea, w1); fma4(a2[0], ea, w2);
        fma4(a1[1], eb, w1); fma4(a2[1], eb, w2);
    }
    float4 b1 = *(const float4*)&bs[g*4];
    float4 b2 = *(const float4*)&bs[H + g*4];
    #pragma unroll
    for (int j = 0; j < 2; j++){
        int row = r0 + 8*j;
        float4 s1 = silu4(a1[j], b1);
        float4 s2 = silu4(a2[j], b2);
        int s = snd_s[row], r = rcv_s[row];
        #pragma unroll
        for (int l = 0; l < LD; l++){
            float dl = dij_s[row][l];
            float4 vc = *(const float4*)&vec[((size_t)s*LD + l)*H + g*4];
            float4 m = make_float4(fmaf(vc.x, s1.x, dl*s2.x),
                                   fmaf(vc.y, s1.y, dl*s2.y),
                                   fmaf(vc.z, s1.z, dl*s2.z),
                                   fmaf(vc.w, s1.w, dl*s2.w));
            float* dst = &vec_agg[((size_t)r*LD + l)*H + g*4];
            atomicAdd(dst+0, m.x); atomicAdd(dst+1, m.y);
            atomicAdd(dst+2, m.z); atomicAdd(dst+3, m.w);
        }
    }
}

// ---------------------------------------------------------------------------
// K4: df_ij = silu(ef@Wf+bf) * w_dot, with
//     w_dot = (A.B) - a*b*(2 - |d|^2), A = Vt[rcv], B = Vs[snd].
// 16 edges per block; Wf (64KB) + rows (8KB) in LDS -> 2 blocks/CU.
// ---------------------------------------------------------------------------
__global__ __launch_bounds__(256) void edge_df(
    const float* __restrict__ ef, const float* __restrict__ Wf, const float* __restrict__ bf_,
    const int* __restrict__ snd, const int* __restrict__ rcv,
    const float* __restrict__ dij,
    const float* __restrict__ Vt, const float* __restrict__ Vs,
    float* __restrict__ df)
{
    __shared__ float wf_s[H*H];
    __shared__ float e_s[16*H];
    __shared__ int   snd_s[16];
    __shared__ int   rcv_s[16];
    __shared__ float dij_s[16][LD];

    const int tid = threadIdx.x;
    const size_t e0 = (size_t)blockIdx.x * 16;
    for (int i = tid; i < H*H/4; i += 256)
        ((float4*)wf_s)[i] = ((const float4*)Wf)[i];
    for (int i = tid; i < 16*H/4; i += 256)
        ((float4*)e_s)[i] = ((const float4*)(ef + e0*H))[i];
    if (tid < 16){ snd_s[tid] = snd[e0+tid]; rcv_s[tid] = rcv[e0+tid]; }
    if (tid < 16*LD) ((float*)dij_s)[tid] = dij[e0*LD + tid];
    __syncthreads();

    const int g = tid & 31, r0 = tid >> 5;
    float4 af[2]; af[0]=f4z(); af[1]=f4z();
    for (int kk = 0; kk < H; kk++){
        float4 w4 = *(float4*)&wf_s[kk*H + g*4];
        float ea = e_s[r0*H + kk];
        float eb = e_s[(r0+8)*H + kk];
        fma4(af[0], ea, w4);
        fma4(af[1], eb, w4);
    }
    float4 bf4 = *(const float4*)&bf_[g*4];
    #pragma unroll
    for (int j = 0; j < 2; j++){
        int row = r0 + 8*j;
        float4 f4 = silu4(af[j], bf4);
        int s = snd_s[row], r = rcv_s[row];
        float4 AB = f4z(), aa = f4z(), bb = f4z();
        float dd = 0.f;
        #pragma unroll
        for (int l = 0; l < LD; l++){
            float dl = dij_s[row][l];
            dd = fmaf(dl, dl, dd);
            float4 A = *(const float4*)&Vt[((size_t)r*LD + l)*H + g*4];
            float4 B = *(const float4*)&Vs[((size_t)s*LD + l)*H + g*4];
            AB.x = fmaf(A.x, B.x, AB.x); AB.y = fmaf(A.y, B.y, AB.y);
            AB.z = fmaf(A.z, B.z, AB.z); AB.w = fmaf(A.w, B.w, AB.w);
            aa.x = fmaf(A.x, dl, aa.x);  aa.y = fmaf(A.y, dl, aa.y);
            aa.z = fmaf(A.z, dl, aa.z);  aa.w = fmaf(A.w, dl, aa.w);
            bb.x = fmaf(B.x, dl, bb.x);  bb.y = fmaf(B.y, dl, bb.y);
            bb.z = fmaf(B.z, dl, bb.z);  bb.w = fmaf(B.w, dl, bb.w);
        }
        float c = 2.0f - dd;
        float4 o = make_float4(f4.x*(AB.x - aa.x*bb.x*c),
                               f4.y*(AB.y - aa.y*bb.y*c),
                               f4.z*(AB.z - aa.z*bb.z*c),
                               f4.w*(AB.w - aa.w*bb.w*c));
        *(float4*)&df[(e0 + row)*H + g*4] = o;
    }
}

// ---------------------------------------------------------------------------
// K5: per-node epilogue: o123 = node_agg@Wo + bo; dx = vec_dot*o2 + o3;
//     dvec = vec3*o1 + vec_agg.
// ---------------------------------------------------------------------------
__global__ __launch_bounds__(128) void node_post(
    const float* __restrict__ node_agg, const float* __restrict__ Wo, const float* __restrict__ bo,
    const float* __restrict__ vdot, const float* __restrict__ vec3, const float* __restrict__ vec_agg,
    float* __restrict__ dx, float* __restrict__ dvec)
{
    const int n = blockIdx.x, h = threadIdx.x;
    __shared__ float na_s[H];
    na_s[h] = node_agg[(size_t)n*H + h];
    __syncthreads();
    float o1 = bo[h], o2 = bo[H + h], o3 = bo[2*H + h];
    for (int kk = 0; kk < H; kk++){
        float a = na_s[kk];
        o1 = fmaf(a, Wo[kk*(3*H) + h], o1);
        o2 = fmaf(a, Wo[kk*(3*H) + H + h], o2);
        o3 = fmaf(a, Wo[kk*(3*H) + 2*H + h], o3);
    }
    dx[(size_t)n*H + h] = fmaf(vdot[(size_t)n*H + h], o2, o3);
    #pragma unroll
    for (int l = 0; l < LD; l++){
        size_t i = ((size_t)n*LD + l)*H + h;
        dvec[i] = fmaf(vec3[i], o1, vec_agg[i]);
    }
}

// ---------------------------------------------------------------------------
extern "C" void kernel_launch(void* const* d_in, const int* in_sizes, int n_in,
                              void* d_out, int out_size, void* d_ws, size_t ws_size,
                              hipStream_t stream) {
    const float* nf    = (const float*)d_in[0];
    const float* ef    = (const float*)d_in[1];
    const float* vf    = (const float*)d_in[2];
    const float* dist  = (const float*)d_in[3];
    const float* dij   = (const float*)d_in[4];
    const int*   snd   = (const int*)d_in[5];
    const int*   rcv   = (const int*)d_in[6];
    const float* ln_s  = (const float*)d_in[7];
    const float* ln_b  = (const float*)d_in[8];
    const float* vlnw  = (const float*)d_in[9];
    const float* W_vec = (const float*)d_in[10];
    const float* Wq    = (const float*)d_in[11];
    const float* bq    = (const float*)d_in[12];
    const float* Wk    = (const float*)d_in[13];
    const float* bk    = (const float*)d_in[14];
    const float* Wv    = (const float*)d_in[15];
    const float* bv    = (const float*)d_in[16];
    const float* Wdk   = (const float*)d_in[17];
    const float* bdk   = (const float*)d_in[18];
    const float* Wdv   = (const float*)d_in[19];
    const float* bdv   = (const float*)d_in[20];
    const float* Ws    = (const float*)d_in[21];
    const float* bs    = (const float*)d_in[22];
    const float* Wo    = (const float*)d_in[23];
    const float* bo    = (const float*)d_in[24];
    const float* Wf    = (const float*)d_in[25];
    const float* bf_   = (const float*)d_in[26];
    const float* Wsrc  = (const float*)d_in[27];
    const float* Wtrg  = (const float*)d_in[28];

    float* out  = (float*)d_out;
    float* dx   = out;                                  // [NN, H]
    float* df   = out + (size_t)NN*H;                   // [NE, H]
    float* dvec = df + (size_t)NE*H;                    // [NN, LD, H]

    float* w = (float*)d_ws;
    size_t off = 0;
    float* q        = w + off; off += (size_t)NN*H;      // 1.28M
    float* k        = w + off; off += (size_t)NN*H;
    float* v        = w + off; off += (size_t)NN*H;
    float* vec      = w + off; off += (size_t)NN*LD*H;   // 10.24M
    float* vdot     = w + off; off += (size_t)NN*H;
    float* vec3     = w + off; off += (size_t)NN*LD*H;
    float* Vt       = w + off; off += (size_t)NN*LD*H;
    float* Vs       = w + off; off += (size_t)NN*LD*H;
    float* vj       = w + off; off += (size_t)NE*H;      // 20.48M
    float* node_agg = w + off; off += (size_t)NN*H;
    float* vec_agg  = w + off; off += (size_t)NN*LD*H;

    hipMemsetAsync(node_agg, 0, (size_t)NN*H*sizeof(float), stream);
    hipMemsetAsync(vec_agg, 0, (size_t)NN*LD*H*sizeof(float), stream);

    node_pre<<<NN, 128, 0, stream>>>(nf, vf, ln_s, ln_b, vlnw, W_vec,
                                     Wq, bq, Wk, bk, Wv, bv, Wtrg, Wsrc,
                                     q, k, v, vec, vdot, vec3, Vt, Vs);

    edge_attn<<<NE/32, 256, 0, stream>>>(ef, Wdk, bdk, Wdv, bdv, snd, rcv, dist,
                                         q, k, v, vj, node_agg);

    edge_s_scatter<<<NE/16, 256, 0, stream>>>(vj, Ws, bs, snd, rcv, dij, vec, vec_agg);

    edge_df<<<NE/16, 256, 0, stream>>>(ef, Wf, bf_, snd, rcv, dij, Vt, Vs, df);

    node_post<<<NN, 128, 0, stream>>>(node_agg, Wo, bo, vdot, vec3, vec_agg, dx, dvec);
}

// Round 2
// 1176.130 us; speedup vs baseline: 2.7521x; 2.7521x over previous
//
#include <hip/hip_runtime.h>
#include <math.h>

#define NN 10000
#define NE 160000
#define H  128
#define LD 8

typedef unsigned short ushort_t;

__device__ __forceinline__ float silu_f(float x){ return x / (1.0f + expf(-x)); }
__device__ __forceinline__ float4 f4z(){ return make_float4(0.f,0.f,0.f,0.f); }

__device__ __forceinline__ void fma4(float4& acc, float s, const float4 w){
    acc.x = fmaf(s, w.x, acc.x);
    acc.y = fmaf(s, w.y, acc.y);
    acc.z = fmaf(s, w.z, acc.z);
    acc.w = fmaf(s, w.w, acc.w);
}

__device__ __forceinline__ float4 silu4(float4 a, float4 b){
    return make_float4(silu_f(a.x+b.x), silu_f(a.y+b.y), silu_f(a.z+b.z), silu_f(a.w+b.w));
}

__device__ __forceinline__ ushort_t f2bf(float f){
    union { float f; unsigned int u; } x; x.f = f;
    unsigned int r = x.u + 0x7FFFu + ((x.u >> 16) & 1u);
    return (ushort_t)(r >> 16);
}
__device__ __forceinline__ float bf2f(ushort_t u){
    union { unsigned int u; float f; } x; x.u = ((unsigned int)u) << 16; return x.f;
}

// ---------------------------------------------------------------------------
// Sort edges by receiver: histogram -> exclusive scan -> rank scatter.
// ---------------------------------------------------------------------------
__global__ void k_hist(const int* __restrict__ rcv, int* __restrict__ cnt){
    int e = blockIdx.x * 256 + threadIdx.x;
    if (e < NE) atomicAdd(&cnt[rcv[e]], 1);
}

__global__ __launch_bounds__(256) void k_scan(const int* __restrict__ cnt, int* __restrict__ offs){
    __shared__ int part[256];
    const int t = threadIdx.x;
    const int CH = 40;              // 256*40 >= 10000 (250 threads used)
    int loc[CH];
    int base = t * CH;
    int lsum = 0;
    if (base < NN){
        #pragma unroll
        for (int i = 0; i < CH; i++){ loc[i] = cnt[base + i]; lsum += loc[i]; }
    }
    part[t] = lsum;
    __syncthreads();
    for (int off = 1; off < 256; off <<= 1){
        int v = (t >= off) ? part[t - off] : 0;
        __syncthreads();
        part[t] += v;
        __syncthreads();
    }
    int ex = part[t] - lsum;
    if (base < NN){
        int run = ex;
        #pragma unroll
        for (int i = 0; i < CH; i++){ offs[base + i] = run; run += loc[i]; }
    }
    if (t == 255) offs[NN] = part[255];
}

__global__ void k_scatter(const int* __restrict__ rcv, const int* __restrict__ offs,
                          int* __restrict__ cnt2, int* __restrict__ eidx){
    int e = blockIdx.x * 256 + threadIdx.x;
    if (e < NE){
        int r = rcv[e];
        int p = atomicAdd(&cnt2[r], 1);
        eidx[offs[r] + p] = e;
    }
}

// ---------------------------------------------------------------------------
// K1: per-node: LayerNorm -> x; q,k,v; vec = vf*vln_w; vec123 -> vec_dot,vec3;
//     Vt = vec@Wtrg; Vs = vec@Wsrc.
// ---------------------------------------------------------------------------
__global__ __launch_bounds__(128) void node_pre(
    const float* __restrict__ nf, const float* __restrict__ vf,
    const float* __restrict__ ln_s, const float* __restrict__ ln_b,
    const float* __restrict__ vlnw, const float* __restrict__ W_vec,
    const float* __restrict__ Wq, const float* __restrict__ bq,
    const float* __restrict__ Wk, const float* __restrict__ bk,
    const float* __restrict__ Wv, const float* __restrict__ bv,
    const float* __restrict__ Wtrg, const float* __restrict__ Wsrc,
    float* __restrict__ q, float* __restrict__ k, float* __restrict__ v,
    float* __restrict__ vec, float* __restrict__ vdot, float* __restrict__ vec3,
    float* __restrict__ Vt, float* __restrict__ Vs)
{
    const int n = blockIdx.x;
    const int h = threadIdx.x;
    __shared__ float x_s[H];
    __shared__ float vec_s[LD][H];
    __shared__ float red[4];

    float xv = nf[(size_t)n*H + h];
    float s1 = xv, s2 = xv*xv;
    #pragma unroll
    for (int o = 32; o >= 1; o >>= 1){
        s1 += __shfl_xor(s1, o, 64);
        s2 += __shfl_xor(s2, o, 64);
    }
    const int wid = h >> 6;
    if ((h & 63) == 0){ red[wid] = s1; red[2+wid] = s2; }
    __syncthreads();
    float mean = (red[0] + red[1]) * (1.0f/H);
    float var  = (red[2] + red[3]) * (1.0f/H) - mean*mean;
    float x = (xv - mean) * rsqrtf(var + 1e-5f) * ln_s[h] + ln_b[h];
    x_s[h] = x;
    float w = vlnw[h];
    #pragma unroll
    for (int l = 0; l < LD; l++){
        size_t i = ((size_t)n*LD + l)*H + h;
        float t = vf[i] * w;
        vec_s[l][h] = t;
        vec[i] = t;
    }
    __syncthreads();

    float aq = bq[h], ak = bk[h], av = bv[h];
    float a1[LD], a2[LD], a3[LD], at[LD], as_[LD];
    #pragma unroll
    for (int l = 0; l < LD; l++){ a1[l]=0.f; a2[l]=0.f; a3[l]=0.f; at[l]=0.f; as_[l]=0.f; }

    for (int kk = 0; kk < H; kk++){
        float xk = x_s[kk];
        aq = fmaf(xk, Wq[kk*H + h], aq);
        ak = fmaf(xk, Wk[kk*H + h], ak);
        av = fmaf(xk, Wv[kk*H + h], av);
        float w1 = W_vec[kk*(3*H) + h];
        float w2 = W_vec[kk*(3*H) + H + h];
        float w3 = W_vec[kk*(3*H) + 2*H + h];
        float wt = Wtrg[kk*H + h];
        float ws = Wsrc[kk*H + h];
        #pragma unroll
        for (int l = 0; l < LD; l++){
            float vk = vec_s[l][kk];
            a1[l] = fmaf(vk, w1, a1[l]);
            a2[l] = fmaf(vk, w2, a2[l]);
            a3[l] = fmaf(vk, w3, a3[l]);
            at[l] = fmaf(vk, wt, at[l]);
            as_[l]= fmaf(vk, ws, as_[l]);
        }
    }
    q[(size_t)n*H + h] = aq;
    k[(size_t)n*H + h] = ak;
    v[(size_t)n*H + h] = av;
    float vd = 0.f;
    #pragma unroll
    for (int l = 0; l < LD; l++) vd = fmaf(a1[l], a2[l], vd);
    vdot[(size_t)n*H + h] = vd;
    #pragma unroll
    for (int l = 0; l < LD; l++){
        size_t i = ((size_t)n*LD + l)*H + h;
        vec3[i] = a3[l];
        Vt[i]   = at[l];
        Vs[i]   = as_[l];
    }
}

// ---------------------------------------------------------------------------
// K2: dk/dv GEMV + head attention + vj (NO atomics). Column-half per blockIdx.y
// so LDS = 64KB weights + 16KB rows = 80KB -> 2 blocks/CU.
// 32 edges/block, 256 threads: g=tid&15 owns 4 cols of the 64-col half,
// r0=tid>>4 owns rows r0, r0+16.
// ---------------------------------------------------------------------------
__global__ __launch_bounds__(256) void edge_attn(
    const float* __restrict__ ef,
    const float* __restrict__ Wdk, const float* __restrict__ bdk,
    const float* __restrict__ Wdv, const float* __restrict__ bdv,
    const int* __restrict__ snd, const int* __restrict__ rcv,
    const float* __restrict__ dist,
    const float* __restrict__ q, const float* __restrict__ k, const float* __restrict__ v,
    float* __restrict__ vj)
{
    __shared__ float wdk_s[H][64];
    __shared__ float wdv_s[H][64];
    __shared__ float e_s[32][H];

    const int tid = threadIdx.x;
    const int by = blockIdx.y;           // column half: cols [by*64, by*64+64)
    const size_t e0 = (size_t)blockIdx.x * 32;

    for (int i = tid; i < H*16; i += 256){          // 128 rows x 16 float4
        int row = i >> 4, c4 = i & 15;
        *(float4*)&wdk_s[row][c4*4] = *(const float4*)&Wdk[row*H + by*64 + c4*4];
        *(float4*)&wdv_s[row][c4*4] = *(const float4*)&Wdv[row*H + by*64 + c4*4];
    }
    for (int i = tid; i < 32*H/4; i += 256)
        ((float4*)e_s)[i] = ((const float4*)(ef + e0*H))[i];
    __syncthreads();

    const int g = tid & 15, r0 = tid >> 4;
    float4 adk[2], adv[2];
    adk[0]=f4z(); adk[1]=f4z(); adv[0]=f4z(); adv[1]=f4z();

    for (int kk = 0; kk < H; kk++){
        float4 wk4 = *(float4*)&wdk_s[kk][g*4];
        float4 wv4 = *(float4*)&wdv_s[kk][g*4];
        float ea = e_s[r0][kk];
        float eb = e_s[r0+16][kk];
        fma4(adk[0], ea, wk4); fma4(adv[0], ea, wv4);
        fma4(adk[1], eb, wk4); fma4(adv[1], eb, wv4);
    }
    float4 bk4 = *(const float4*)&bdk[by*64 + g*4];
    float4 bv4 = *(const float4*)&bdv[by*64 + g*4];
    #pragma unroll
    for (int j = 0; j < 2; j++){
        int row = r0 + 16*j;
        float4 sdk = silu4(adk[j], bk4);
        float4 sdv = silu4(adv[j], bv4);
        int s = snd[e0 + row];
        int r = rcv[e0 + row];
        float d = dist[e0 + row];
        float cut = (d < 5.0f) ? 0.5f*(cosf(d*0.6283185307179586f) + 1.0f) : 0.0f;
        float4 q4 = *(const float4*)&q[(size_t)r*H + by*64 + g*4];
        float4 k4 = *(const float4*)&k[(size_t)s*H + by*64 + g*4];
        float p = q4.x*k4.x*sdk.x + q4.y*k4.y*sdk.y
                + q4.z*k4.z*sdk.z + q4.w*k4.w*sdk.w;
        p += __shfl_xor(p, 1, 64);   // 4 adjacent g-lanes = 16 cols = 1 head
        p += __shfl_xor(p, 2, 64);
        float attn = silu_f(p) * cut;
        float4 v4 = *(const float4*)&v[(size_t)s*H + by*64 + g*4];
        float4 o = make_float4(v4.x*sdv.x*attn, v4.y*sdv.y*attn,
                               v4.z*sdv.z*attn, v4.w*sdv.w*attn);
        *(float4*)&vj[(e0 + row)*H + by*64 + g*4] = o;
    }
}

// ---------------------------------------------------------------------------
// K3: s12 = silu(vj@Ws + bs) [E,256] stored bf16. Column-half per blockIdx.y,
// 32 edges/block: LDS = 64KB Ws-half + 16KB vj rows = 80KB -> 2 blocks/CU.
// ---------------------------------------------------------------------------
__global__ __launch_bounds__(256) void edge_s(
    const float* __restrict__ vj, const float* __restrict__ Ws, const float* __restrict__ bs,
    ushort_t* __restrict__ s12)
{
    __shared__ float ws_s[H][H];
    __shared__ float vj_s[32][H];

    const int tid = threadIdx.x;
    const int by = blockIdx.y;
    const size_t e0 = (size_t)blockIdx.x * 32;

    for (int i = tid; i < H*32; i += 256){          // 128 rows x 32 float4
        int row = i >> 5, c4 = i & 31;
        *(float4*)&ws_s[row][c4*4] = *(const float4*)&Ws[row*256 + by*H + c4*4];
    }
    for (int i = tid; i < 32*H/4; i += 256)
        ((float4*)vj_s)[i] = ((const float4*)(vj + e0*H))[i];
    __syncthreads();

    const int g = tid & 31, r0 = tid >> 5;
    float4 acc[4];
    #pragma unroll
    for (int j = 0; j < 4; j++) acc[j] = f4z();

    for (int kk = 0; kk < H; kk++){
        float4 w4 = *(float4*)&ws_s[kk][g*4];
        #pragma unroll
        for (int j = 0; j < 4; j++){
            float e = vj_s[r0 + 8*j][kk];
            fma4(acc[j], e, w4);
        }
    }
    float4 b4 = *(const float4*)&bs[by*H + g*4];
    #pragma unroll
    for (int j = 0; j < 4; j++){
        int row = r0 + 8*j;
        float4 s = silu4(acc[j], b4);
        uint2 u;
        u.x = (unsigned int)f2bf(s.x) | ((unsigned int)f2bf(s.y) << 16);
        u.y = (unsigned int)f2bf(s.z) | ((unsigned int)f2bf(s.w) << 16);
        *(uint2*)&s12[(e0 + row)*256 + by*H + g*4] = u;
    }
}

// ---------------------------------------------------------------------------
// K4: df_ij = silu(ef@Wf+bf) * w_dot, w_dot = (A.B) - a*b*(2 - |d|^2).
// ---------------------------------------------------------------------------
__global__ __launch_bounds__(256) void edge_df(
    const float* __restrict__ ef, const float* __restrict__ Wf, const float* __restrict__ bf_,
    const int* __restrict__ snd, const int* __restrict__ rcv,
    const float* __restrict__ dij,
    const float* __restrict__ Vt, const float* __restrict__ Vs,
    float* __restrict__ df)
{
    __shared__ float wf_s[H*H];
    __shared__ float e_s[16*H];
    __shared__ int   snd_s[16];
    __shared__ int   rcv_s[16];
    __shared__ float dij_s[16][LD];

    const int tid = threadIdx.x;
    const size_t e0 = (size_t)blockIdx.x * 16;
    for (int i = tid; i < H*H/4; i += 256)
        ((float4*)wf_s)[i] = ((const float4*)Wf)[i];
    for (int i = tid; i < 16*H/4; i += 256)
        ((float4*)e_s)[i] = ((const float4*)(ef + e0*H))[i];
    if (tid < 16){ snd_s[tid] = snd[e0+tid]; rcv_s[tid] = rcv[e0+tid]; }
    if (tid < 16*LD) ((float*)dij_s)[tid] = dij[e0*LD + tid];
    __syncthreads();

    const int g = tid & 31, r0 = tid >> 5;
    float4 af[2]; af[0]=f4z(); af[1]=f4z();
    for (int kk = 0; kk < H; kk++){
        float4 w4 = *(float4*)&wf_s[kk*H + g*4];
        float ea = e_s[r0*H + kk];
        float eb = e_s[(r0+8)*H + kk];
        fma4(af[0], ea, w4);
        fma4(af[1], eb, w4);
    }
    float4 bf4 = *(const float4*)&bf_[g*4];
    #pragma unroll
    for (int j = 0; j < 2; j++){
        int row = r0 + 8*j;
        float4 f4 = silu4(af[j], bf4);
        int s = snd_s[row], r = rcv_s[row];
        float4 AB = f4z(), aa = f4z(), bb = f4z();
        float dd = 0.f;
        #pragma unroll
        for (int l = 0; l < LD; l++){
            float dl = dij_s[row][l];
            dd = fmaf(dl, dl, dd);
            float4 A = *(const float4*)&Vt[((size_t)r*LD + l)*H + g*4];
            float4 B = *(const float4*)&Vs[((size_t)s*LD + l)*H + g*4];
            AB.x = fmaf(A.x, B.x, AB.x); AB.y = fmaf(A.y, B.y, AB.y);
            AB.z = fmaf(A.z, B.z, AB.z); AB.w = fmaf(A.w, B.w, AB.w);
            aa.x = fmaf(A.x, dl, aa.x);  aa.y = fmaf(A.y, dl, aa.y);
            aa.z = fmaf(A.z, dl, aa.z);  aa.w = fmaf(A.w, dl, aa.w);
            bb.x = fmaf(B.x, dl, bb.x);  bb.y = fmaf(B.y, dl, bb.y);
            bb.z = fmaf(B.z, dl, bb.z);  bb.w = fmaf(B.w, dl, bb.w);
        }
        float c = 2.0f - dd;
        float4 o = make_float4(f4.x*(AB.x - aa.x*bb.x*c),
                               f4.y*(AB.y - aa.y*bb.y*c),
                               f4.z*(AB.z - aa.z*bb.z*c),
                               f4.w*(AB.w - aa.w*bb.w*c));
        *(float4*)&df[(e0 + row)*H + g*4] = o;
    }
}

// ---------------------------------------------------------------------------
// K5: per-receiver gather (edges sorted by receiver): node_agg & vec_agg in
// registers, then fused node_post: o123 = node_agg@Wo+bo; dx; dvec.
// ---------------------------------------------------------------------------
__global__ __launch_bounds__(128) void node_gather(
    const int* __restrict__ offs, const int* __restrict__ eidx, const int* __restrict__ snd,
    const float* __restrict__ vj, const ushort_t* __restrict__ s12,
    const float* __restrict__ dij, const float* __restrict__ vec,
    const float* __restrict__ Wo, const float* __restrict__ bo,
    const float* __restrict__ vdot, const float* __restrict__ vec3,
    float* __restrict__ dx, float* __restrict__ dvec)
{
    const int n = blockIdx.x, h = threadIdx.x;
    const int beg = offs[n], end = offs[n+1];
    float na = 0.f;
    float av[LD];
    #pragma unroll
    for (int l = 0; l < LD; l++) av[l] = 0.f;

    for (int i = beg; i < end; i++){
        int e = eidx[i];
        int s = snd[e];
        float vjv = vj[(size_t)e*H + h];
        float s1 = bf2f(s12[(size_t)e*256 + h]);
        float s2 = bf2f(s12[(size_t)e*256 + 128 + h]);
        na += vjv;
        float4 d0 = *(const float4*)&dij[(size_t)e*LD];
        float4 d1 = *(const float4*)&dij[(size_t)e*LD + 4];
        const float* vr = &vec[(size_t)s*LD*H + h];
        av[0] = fmaf(vr[0*H], s1, fmaf(d0.x, s2, av[0]));
        av[1] = fmaf(vr[1*H], s1, fmaf(d0.y, s2, av[1]));
        av[2] = fmaf(vr[2*H], s1, fmaf(d0.z, s2, av[2]));
        av[3] = fmaf(vr[3*H], s1, fmaf(d0.w, s2, av[3]));
        av[4] = fmaf(vr[4*H], s1, fmaf(d1.x, s2, av[4]));
        av[5] = fmaf(vr[5*H], s1, fmaf(d1.y, s2, av[5]));
        av[6] = fmaf(vr[6*H], s1, fmaf(d1.z, s2, av[6]));
        av[7] = fmaf(vr[7*H], s1, fmaf(d1.w, s2, av[7]));
    }

    __shared__ float na_s[H];
    na_s[h] = na;
    __syncthreads();
    float o1 = bo[h], o2 = bo[H + h], o3 = bo[2*H + h];
    for (int kk = 0; kk < H; kk++){
        float a = na_s[kk];
        o1 = fmaf(a, Wo[kk*(3*H) + h], o1);
        o2 = fmaf(a, Wo[kk*(3*H) + H + h], o2);
        o3 = fmaf(a, Wo[kk*(3*H) + 2*H + h], o3);
    }
    dx[(size_t)n*H + h] = fmaf(vdot[(size_t)n*H + h], o2, o3);
    #pragma unroll
    for (int l = 0; l < LD; l++){
        size_t i2 = ((size_t)n*LD + l)*H + h;
        dvec[i2] = fmaf(vec3[i2], o1, av[l]);
    }
}

// ---------------------------------------------------------------------------
extern "C" void kernel_launch(void* const* d_in, const int* in_sizes, int n_in,
                              void* d_out, int out_size, void* d_ws, size_t ws_size,
                              hipStream_t stream) {
    const float* nf    = (const float*)d_in[0];
    const float* ef    = (const float*)d_in[1];
    const float* vf    = (const float*)d_in[2];
    const float* dist  = (const float*)d_in[3];
    const float* dij   = (const float*)d_in[4];
    const int*   snd   = (const int*)d_in[5];
    const int*   rcv   = (const int*)d_in[6];
    const float* ln_s  = (const float*)d_in[7];
    const float* ln_b  = (const float*)d_in[8];
    const float* vlnw  = (const float*)d_in[9];
    const float* W_vec = (const float*)d_in[10];
    const float* Wq    = (const float*)d_in[11];
    const float* bq    = (const float*)d_in[12];
    const float* Wk    = (const float*)d_in[13];
    const float* bk    = (const float*)d_in[14];
    const float* Wv    = (const float*)d_in[15];
    const float* bv    = (const float*)d_in[16];
    const float* Wdk   = (const float*)d_in[17];
    const float* bdk   = (const float*)d_in[18];
    const float* Wdv   = (const float*)d_in[19];
    const float* bdv   = (const float*)d_in[20];
    const float* Ws    = (const float*)d_in[21];
    const float* bs    = (const float*)d_in[22];
    const float* Wo    = (const float*)d_in[23];
    const float* bo    = (const float*)d_in[24];
    const float* Wf    = (const float*)d_in[25];
    const float* bf_   = (const float*)d_in[26];
    const float* Wsrc  = (const float*)d_in[27];
    const float* Wtrg  = (const float*)d_in[28];

    float* out  = (float*)d_out;
    float* dx   = out;                                  // [NN, H]
    float* df   = out + (size_t)NN*H;                   // [NE, H]
    float* dvec = df + (size_t)NE*H;                    // [NN, LD, H]

    float* w = (float*)d_ws;
    size_t off = 0;
    float* q    = w + off; off += (size_t)NN*H;
    float* k    = w + off; off += (size_t)NN*H;
    float* v    = w + off; off += (size_t)NN*H;
    float* vec  = w + off; off += (size_t)NN*LD*H;
    float* vdot = w + off; off += (size_t)NN*H;
    float* vec3 = w + off; off += (size_t)NN*LD*H;
    float* Vt   = w + off; off += (size_t)NN*LD*H;
    float* Vs   = w + off; off += (size_t)NN*LD*H;
    float* vj   = w + off; off += (size_t)NE*H;
    // s12 (bf16, E*256 = 81.92MB) aliases Vt+Vs (dead after edge_df)
    ushort_t* s12 = (ushort_t*)Vt;
    int* cnt  = (int*)(w + off); off += NN;
    int* cnt2 = (int*)(w + off); off += NN;
    int* offs = (int*)(w + off); off += NN + 1;
    int* eidx = (int*)(w + off); off += NE;

    hipMemsetAsync(cnt,  0, NN*sizeof(int), stream);
    hipMemsetAsync(cnt2, 0, NN*sizeof(int), stream);

    k_hist<<<(NE+255)/256, 256, 0, stream>>>(rcv, cnt);
    k_scan<<<1, 256, 0, stream>>>(cnt, offs);
    k_scatter<<<(NE+255)/256, 256, 0, stream>>>(rcv, offs, cnt2, eidx);

    node_pre<<<NN, 128, 0, stream>>>(nf, vf, ln_s, ln_b, vlnw, W_vec,
                                     Wq, bq, Wk, bk, Wv, bv, Wtrg, Wsrc,
                                     q, k, v, vec, vdot, vec3, Vt, Vs);

    edge_attn<<<dim3(NE/32, 2), 256, 0, stream>>>(ef, Wdk, bdk, Wdv, bdv, snd, rcv, dist,
                                                  q, k, v, vj);

    edge_df<<<NE/16, 256, 0, stream>>>(ef, Wf, bf_, snd, rcv, dij, Vt, Vs, df);

    edge_s<<<dim3(NE/32, 2), 256, 0, stream>>>(vj, Ws, bs, s12);

    node_gather<<<NN, 128, 0, stream>>>(offs, eidx, snd, vj, s12, dij, vec,
                                        Wo, bo, vdot, vec3, dx, dvec);
}

// Round 3
// 1042.926 us; speedup vs baseline: 3.1036x; 1.1277x over previous
//
#include <hip/hip_runtime.h>
#include <math.h>

#define NN 10000
#define NE 160000
#define H  128
#define LD 8

typedef unsigned short ushort_t;

__device__ __forceinline__ float silu_f(float x){ return x / (1.0f + expf(-x)); }
__device__ __forceinline__ float4 f4z(){ return make_float4(0.f,0.f,0.f,0.f); }

__device__ __forceinline__ void fma4(float4& acc, float s, const float4 w){
    acc.x = fmaf(s, w.x, acc.x);
    acc.y = fmaf(s, w.y, acc.y);
    acc.z = fmaf(s, w.z, acc.z);
    acc.w = fmaf(s, w.w, acc.w);
}

__device__ __forceinline__ float4 silu4(float4 a, float4 b){
    return make_float4(silu_f(a.x+b.x), silu_f(a.y+b.y), silu_f(a.z+b.z), silu_f(a.w+b.w));
}

__device__ __forceinline__ ushort_t f2bf(float f){
    union { float f; unsigned int u; } x; x.f = f;
    unsigned int r = x.u + 0x7FFFu + ((x.u >> 16) & 1u);
    return (ushort_t)(r >> 16);
}
__device__ __forceinline__ float bf2f(unsigned int u){
    union { unsigned int u; float f; } x; x.u = u << 16; return x.f;
}
__device__ __forceinline__ float bf2f_hi(unsigned int u){
    union { unsigned int u; float f; } x; x.u = u & 0xffff0000u; return x.f;
}
__device__ __forceinline__ float bf2f_lo(unsigned int u){
    union { unsigned int u; float f; } x; x.u = u << 16; return x.f;
}

// ---------------------------------------------------------------------------
// Sort edges by receiver: histogram -> exclusive scan -> rank scatter.
// ---------------------------------------------------------------------------
__global__ void k_hist(const int* __restrict__ rcv, int* __restrict__ cnt){
    int e = blockIdx.x * 256 + threadIdx.x;
    if (e < NE) atomicAdd(&cnt[rcv[e]], 1);
}

__global__ __launch_bounds__(256) void k_scan(const int* __restrict__ cnt, int* __restrict__ offs){
    __shared__ int part[256];
    const int t = threadIdx.x;
    const int CH = 40;              // 256*40 >= 10000
    int loc[CH];
    int base = t * CH;
    int lsum = 0;
    if (base < NN){
        #pragma unroll
        for (int i = 0; i < CH; i++){ loc[i] = cnt[base + i]; lsum += loc[i]; }
    }
    part[t] = lsum;
    __syncthreads();
    for (int off = 1; off < 256; off <<= 1){
        int v = (t >= off) ? part[t - off] : 0;
        __syncthreads();
        part[t] += v;
        __syncthreads();
    }
    int ex = part[t] - lsum;
    if (base < NN){
        int run = ex;
        #pragma unroll
        for (int i = 0; i < CH; i++){ offs[base + i] = run; run += loc[i]; }
    }
    if (t == 255) offs[NN] = part[255];
}

__global__ void k_scatter(const int* __restrict__ rcv, const int* __restrict__ offs,
                          int* __restrict__ cnt2, int* __restrict__ eidx){
    int e = blockIdx.x * 256 + threadIdx.x;
    if (e < NE){
        int r = rcv[e];
        int p = atomicAdd(&cnt2[r], 1);
        eidx[offs[r] + p] = e;
    }
}

// ---------------------------------------------------------------------------
// K1: per-node: LayerNorm -> x; q,k,v; vec = vf*vln_w (stored bf16);
//     vec123 -> vec_dot,vec3; Vt/Vs = vec@Wtrg/Wsrc stored bf16.
// ---------------------------------------------------------------------------
__global__ __launch_bounds__(128) void node_pre(
    const float* __restrict__ nf, const float* __restrict__ vf,
    const float* __restrict__ ln_s, const float* __restrict__ ln_b,
    const float* __restrict__ vlnw, const float* __restrict__ W_vec,
    const float* __restrict__ Wq, const float* __restrict__ bq,
    const float* __restrict__ Wk, const float* __restrict__ bk,
    const float* __restrict__ Wv, const float* __restrict__ bv,
    const float* __restrict__ Wtrg, const float* __restrict__ Wsrc,
    float* __restrict__ q, float* __restrict__ k, float* __restrict__ v,
    ushort_t* __restrict__ vec_bf, float* __restrict__ vdot, float* __restrict__ vec3,
    ushort_t* __restrict__ Vt, ushort_t* __restrict__ Vs)
{
    const int n = blockIdx.x;
    const int h = threadIdx.x;
    __shared__ float x_s[H];
    __shared__ float vec_s[LD][H];
    __shared__ float red[4];

    float xv = nf[(size_t)n*H + h];
    float s1 = xv, s2 = xv*xv;
    #pragma unroll
    for (int o = 32; o >= 1; o >>= 1){
        s1 += __shfl_xor(s1, o, 64);
        s2 += __shfl_xor(s2, o, 64);
    }
    const int wid = h >> 6;
    if ((h & 63) == 0){ red[wid] = s1; red[2+wid] = s2; }
    __syncthreads();
    float mean = (red[0] + red[1]) * (1.0f/H);
    float var  = (red[2] + red[3]) * (1.0f/H) - mean*mean;
    float x = (xv - mean) * rsqrtf(var + 1e-5f) * ln_s[h] + ln_b[h];
    x_s[h] = x;
    float w = vlnw[h];
    #pragma unroll
    for (int l = 0; l < LD; l++){
        size_t i = ((size_t)n*LD + l)*H + h;
        float t = vf[i] * w;
        vec_s[l][h] = t;
        vec_bf[i] = f2bf(t);
    }
    __syncthreads();

    float aq = bq[h], ak = bk[h], av = bv[h];
    float a1[LD], a2[LD], a3[LD], at[LD], as_[LD];
    #pragma unroll
    for (int l = 0; l < LD; l++){ a1[l]=0.f; a2[l]=0.f; a3[l]=0.f; at[l]=0.f; as_[l]=0.f; }

    for (int kk = 0; kk < H; kk++){
        float xk = x_s[kk];
        aq = fmaf(xk, Wq[kk*H + h], aq);
        ak = fmaf(xk, Wk[kk*H + h], ak);
        av = fmaf(xk, Wv[kk*H + h], av);
        float w1 = W_vec[kk*(3*H) + h];
        float w2 = W_vec[kk*(3*H) + H + h];
        float w3 = W_vec[kk*(3*H) + 2*H + h];
        float wt = Wtrg[kk*H + h];
        float ws = Wsrc[kk*H + h];
        #pragma unroll
        for (int l = 0; l < LD; l++){
            float vk = vec_s[l][kk];
            a1[l] = fmaf(vk, w1, a1[l]);
            a2[l] = fmaf(vk, w2, a2[l]);
            a3[l] = fmaf(vk, w3, a3[l]);
            at[l] = fmaf(vk, wt, at[l]);
            as_[l]= fmaf(vk, ws, as_[l]);
        }
    }
    q[(size_t)n*H + h] = aq;
    k[(size_t)n*H + h] = ak;
    v[(size_t)n*H + h] = av;
    float vd = 0.f;
    #pragma unroll
    for (int l = 0; l < LD; l++) vd = fmaf(a1[l], a2[l], vd);
    vdot[(size_t)n*H + h] = vd;
    #pragma unroll
    for (int l = 0; l < LD; l++){
        size_t i = ((size_t)n*LD + l)*H + h;
        vec3[i] = a3[l];
        Vt[i]   = f2bf(at[l]);
        Vs[i]   = f2bf(as_[l]);
    }
}

// ---------------------------------------------------------------------------
// K2: dk/dv GEMV + head attention -> vj (bf16). Column-half per blockIdx.y.
// ---------------------------------------------------------------------------
__global__ __launch_bounds__(256) void edge_attn(
    const float* __restrict__ ef,
    const float* __restrict__ Wdk, const float* __restrict__ bdk,
    const float* __restrict__ Wdv, const float* __restrict__ bdv,
    const int* __restrict__ snd, const int* __restrict__ rcv,
    const float* __restrict__ dist,
    const float* __restrict__ q, const float* __restrict__ k, const float* __restrict__ v,
    ushort_t* __restrict__ vj)
{
    __shared__ float wdk_s[H][64];
    __shared__ float wdv_s[H][64];
    __shared__ float e_s[32][H];

    const int tid = threadIdx.x;
    const int by = blockIdx.y;           // column half: cols [by*64, by*64+64)
    const size_t e0 = (size_t)blockIdx.x * 32;

    for (int i = tid; i < H*16; i += 256){          // 128 rows x 16 float4
        int row = i >> 4, c4 = i & 15;
        *(float4*)&wdk_s[row][c4*4] = *(const float4*)&Wdk[row*H + by*64 + c4*4];
        *(float4*)&wdv_s[row][c4*4] = *(const float4*)&Wdv[row*H + by*64 + c4*4];
    }
    for (int i = tid; i < 32*H/4; i += 256)
        ((float4*)e_s)[i] = ((const float4*)(ef + e0*H))[i];
    __syncthreads();

    const int g = tid & 15, r0 = tid >> 4;
    float4 adk[2], adv[2];
    adk[0]=f4z(); adk[1]=f4z(); adv[0]=f4z(); adv[1]=f4z();

    for (int kk = 0; kk < H; kk++){
        float4 wk4 = *(float4*)&wdk_s[kk][g*4];
        float4 wv4 = *(float4*)&wdv_s[kk][g*4];
        float ea = e_s[r0][kk];
        float eb = e_s[r0+16][kk];
        fma4(adk[0], ea, wk4); fma4(adv[0], ea, wv4);
        fma4(adk[1], eb, wk4); fma4(adv[1], eb, wv4);
    }
    float4 bk4 = *(const float4*)&bdk[by*64 + g*4];
    float4 bv4 = *(const float4*)&bdv[by*64 + g*4];
    #pragma unroll
    for (int j = 0; j < 2; j++){
        int row = r0 + 16*j;
        float4 sdk = silu4(adk[j], bk4);
        float4 sdv = silu4(adv[j], bv4);
        int s = snd[e0 + row];
        int r = rcv[e0 + row];
        float d = dist[e0 + row];
        float cut = (d < 5.0f) ? 0.5f*(cosf(d*0.6283185307179586f) + 1.0f) : 0.0f;
        float4 q4 = *(const float4*)&q[(size_t)r*H + by*64 + g*4];
        float4 k4 = *(const float4*)&k[(size_t)s*H + by*64 + g*4];
        float p = q4.x*k4.x*sdk.x + q4.y*k4.y*sdk.y
                + q4.z*k4.z*sdk.z + q4.w*k4.w*sdk.w;
        p += __shfl_xor(p, 1, 64);   // 4 adjacent g-lanes = 16 cols = 1 head
        p += __shfl_xor(p, 2, 64);
        float attn = silu_f(p) * cut;
        float4 v4 = *(const float4*)&v[(size_t)s*H + by*64 + g*4];
        float4 o = make_float4(v4.x*sdv.x*attn, v4.y*sdv.y*attn,
                               v4.z*sdv.z*attn, v4.w*sdv.w*attn);
        uint2 u;
        u.x = (unsigned int)f2bf(o.x) | ((unsigned int)f2bf(o.y) << 16);
        u.y = (unsigned int)f2bf(o.z) | ((unsigned int)f2bf(o.w) << 16);
        *(uint2*)&vj[(e0 + row)*H + by*64 + g*4] = u;
    }
}

// ---------------------------------------------------------------------------
// K3: s12 = silu(vj@Ws + bs) [E,256] stored bf16. Column-half per blockIdx.y.
// ---------------------------------------------------------------------------
__global__ __launch_bounds__(256) void edge_s(
    const ushort_t* __restrict__ vj, const float* __restrict__ Ws, const float* __restrict__ bs,
    ushort_t* __restrict__ s12)
{
    __shared__ float ws_s[H][H];
    __shared__ float vj_s[32][H];

    const int tid = threadIdx.x;
    const int by = blockIdx.y;
    const size_t e0 = (size_t)blockIdx.x * 32;

    for (int i = tid; i < H*32; i += 256){          // 128 rows x 32 float4
        int row = i >> 5, c4 = i & 31;
        *(float4*)&ws_s[row][c4*4] = *(const float4*)&Ws[row*256 + by*H + c4*4];
    }
    for (int i = tid; i < 32*16; i += 256){         // 32 rows x 16 uint4 (8 bf16)
        int row = i >> 4, c8 = i & 15;
        uint4 u = *(const uint4*)&vj[(e0 + row)*H + c8*8];
        float* dst = &vj_s[row][c8*8];
        dst[0] = bf2f_lo(u.x); dst[1] = bf2f_hi(u.x) ;
        dst[2] = bf2f_lo(u.y); dst[3] = bf2f_hi(u.y);
        dst[4] = bf2f_lo(u.z); dst[5] = bf2f_hi(u.z);
        dst[6] = bf2f_lo(u.w); dst[7] = bf2f_hi(u.w);
    }
    __syncthreads();

    const int g = tid & 31, r0 = tid >> 5;
    float4 acc[4];
    #pragma unroll
    for (int j = 0; j < 4; j++) acc[j] = f4z();

    for (int kk = 0; kk < H; kk++){
        float4 w4 = *(float4*)&ws_s[kk][g*4];
        #pragma unroll
        for (int j = 0; j < 4; j++){
            float e = vj_s[r0 + 8*j][kk];
            fma4(acc[j], e, w4);
        }
    }
    float4 b4 = *(const float4*)&bs[by*H + g*4];
    #pragma unroll
    for (int j = 0; j < 4; j++){
        int row = r0 + 8*j;
        float4 s = silu4(acc[j], b4);
        uint2 u;
        u.x = (unsigned int)f2bf(s.x) | ((unsigned int)f2bf(s.y) << 16);
        u.y = (unsigned int)f2bf(s.z) | ((unsigned int)f2bf(s.w) << 16);
        *(uint2*)&s12[(e0 + row)*256 + by*H + g*4] = u;
    }
}

// ---------------------------------------------------------------------------
// K4: df_ij = silu(ef@Wf+bf) * w_dot, w_dot = (A.B) - a*b*(2 - |d|^2),
// A = Vt[rcv] (bf16), B = Vs[snd] (bf16). Edges processed in receiver-sorted
// order (Vt gathers hit L1/L2); column-half split per blockIdx.y.
// ---------------------------------------------------------------------------
__global__ __launch_bounds__(256) void edge_df(
    const float* __restrict__ ef, const float* __restrict__ Wf, const float* __restrict__ bf_,
    const int* __restrict__ eidx,
    const int* __restrict__ snd, const int* __restrict__ rcv,
    const float* __restrict__ dij,
    const ushort_t* __restrict__ Vt, const ushort_t* __restrict__ Vs,
    float* __restrict__ df)
{
    __shared__ float wf_s[H][64];
    __shared__ float e_s[16][H];
    __shared__ int   eidx_s[16];
    __shared__ int   snd_s[16];
    __shared__ int   rcv_s[16];
    __shared__ float dij_s[16][LD];

    const int tid = threadIdx.x;
    const int by = blockIdx.y;
    const int p0 = blockIdx.x * 16;      // sorted positions [p0, p0+16)

    if (tid < 16) eidx_s[tid] = eidx[p0 + tid];
    __syncthreads();

    for (int i = tid; i < H*16; i += 256){          // Wf half: 128 rows x 16 f4
        int row = i >> 4, c4 = i & 15;
        *(float4*)&wf_s[row][c4*4] = *(const float4*)&Wf[row*H + by*64 + c4*4];
    }
    for (int i = tid; i < 16*32; i += 256){         // 16 rows x 32 float4
        int row = i >> 5, c4 = i & 31;
        *(float4*)&e_s[row][c4*4] = *(const float4*)&ef[(size_t)eidx_s[row]*H + c4*4];
    }
    if (tid < 16){ snd_s[tid] = snd[eidx_s[tid]]; rcv_s[tid] = rcv[eidx_s[tid]]; }
    if (tid < 16*LD){
        int row = tid >> 3, l = tid & 7;
        dij_s[row][l] = dij[(size_t)eidx_s[row]*LD + l];
    }
    __syncthreads();

    const int g = tid & 15, r0 = tid >> 4;          // 16 cols-of-4, 16 rows
    float4 af = f4z();
    for (int kk = 0; kk < H; kk++){
        float4 w4 = *(float4*)&wf_s[kk][g*4];
        fma4(af, e_s[r0][kk], w4);
    }
    float4 bf4 = *(const float4*)&bf_[by*64 + g*4];
    float4 f4 = silu4(af, bf4);

    const int e = eidx_s[r0];
    const int s = snd_s[r0], r = rcv_s[r0];
    const ushort_t* Ar = Vt + ((size_t)r*LD)*H + by*64 + g*4;
    const ushort_t* Br = Vs + ((size_t)s*LD)*H + by*64 + g*4;

    float4 AB = f4z(), aa = f4z(), bb = f4z();
    float dd = 0.f;
    #pragma unroll
    for (int l = 0; l < LD; l++){
        float dl = dij_s[r0][l];
        dd = fmaf(dl, dl, dd);
        uint2 ua = *(const uint2*)&Ar[(size_t)l*H];
        uint2 ub = *(const uint2*)&Br[(size_t)l*H];
        float Ax = bf2f_lo(ua.x), Ay = bf2f_hi(ua.x), Az = bf2f_lo(ua.y), Aw = bf2f_hi(ua.y);
        float Bx = bf2f_lo(ub.x), By = bf2f_hi(ub.x), Bz = bf2f_lo(ub.y), Bw = bf2f_hi(ub.y);
        AB.x = fmaf(Ax, Bx, AB.x); AB.y = fmaf(Ay, By, AB.y);
        AB.z = fmaf(Az, Bz, AB.z); AB.w = fmaf(Aw, Bw, AB.w);
        aa.x = fmaf(Ax, dl, aa.x); aa.y = fmaf(Ay, dl, aa.y);
        aa.z = fmaf(Az, dl, aa.z); aa.w = fmaf(Aw, dl, aa.w);
        bb.x = fmaf(Bx, dl, bb.x); bb.y = fmaf(By, dl, bb.y);
        bb.z = fmaf(Bz, dl, bb.z); bb.w = fmaf(Bw, dl, bb.w);
    }
    float c = 2.0f - dd;
    float4 o = make_float4(f4.x*(AB.x - aa.x*bb.x*c),
                           f4.y*(AB.y - aa.y*bb.y*c),
                           f4.z*(AB.z - aa.z*bb.z*c),
                           f4.w*(AB.w - aa.w*bb.w*c));
    *(float4*)&df[(size_t)e*H + by*64 + g*4] = o;
}

// ---------------------------------------------------------------------------
// K5: per-receiver gather (edges sorted by receiver): node_agg & vec_agg in
// registers, then fused node_post: o123 = node_agg@Wo+bo; dx; dvec.
// ---------------------------------------------------------------------------
__global__ __launch_bounds__(128) void node_gather(
    const int* __restrict__ offs, const int* __restrict__ eidx, const int* __restrict__ snd,
    const ushort_t* __restrict__ vj, const ushort_t* __restrict__ s12,
    const float* __restrict__ dij, const ushort_t* __restrict__ vec,
    const float* __restrict__ Wo, const float* __restrict__ bo,
    const float* __restrict__ vdot, const float* __restrict__ vec3,
    float* __restrict__ dx, float* __restrict__ dvec)
{
    const int n = blockIdx.x, h = threadIdx.x;
    const int beg = offs[n], end = offs[n+1];
    float na = 0.f;
    float av[LD];
    #pragma unroll
    for (int l = 0; l < LD; l++) av[l] = 0.f;

    for (int i = beg; i < end; i++){
        int e = eidx[i];
        int s = snd[e];
        float vjv = bf2f_lo((unsigned int)vj[(size_t)e*H + h]);
        float s1 = bf2f_lo((unsigned int)s12[(size_t)e*256 + h]);
        float s2 = bf2f_lo((unsigned int)s12[(size_t)e*256 + 128 + h]);
        na += vjv;
        float4 d0 = *(const float4*)&dij[(size_t)e*LD];
        float4 d1 = *(const float4*)&dij[(size_t)e*LD + 4];
        const ushort_t* vr = &vec[(size_t)s*LD*H + h];
        av[0] = fmaf(bf2f_lo((unsigned int)vr[0*H]), s1, fmaf(d0.x, s2, av[0]));
        av[1] = fmaf(bf2f_lo((unsigned int)vr[1*H]), s1, fmaf(d0.y, s2, av[1]));
        av[2] = fmaf(bf2f_lo((unsigned int)vr[2*H]), s1, fmaf(d0.z, s2, av[2]));
        av[3] = fmaf(bf2f_lo((unsigned int)vr[3*H]), s1, fmaf(d0.w, s2, av[3]));
        av[4] = fmaf(bf2f_lo((unsigned int)vr[4*H]), s1, fmaf(d1.x, s2, av[4]));
        av[5] = fmaf(bf2f_lo((unsigned int)vr[5*H]), s1, fmaf(d1.y, s2, av[5]));
        av[6] = fmaf(bf2f_lo((unsigned int)vr[6*H]), s1, fmaf(d1.z, s2, av[6]));
        av[7] = fmaf(bf2f_lo((unsigned int)vr[7*H]), s1, fmaf(d1.w, s2, av[7]));
    }

    __shared__ float na_s[H];
    na_s[h] = na;
    __syncthreads();
    float o1 = bo[h], o2 = bo[H + h], o3 = bo[2*H + h];
    for (int kk = 0; kk < H; kk++){
        float a = na_s[kk];
        o1 = fmaf(a, Wo[kk*(3*H) + h], o1);
        o2 = fmaf(a, Wo[kk*(3*H) + H + h], o2);
        o3 = fmaf(a, Wo[kk*(3*H) + 2*H + h], o3);
    }
    dx[(size_t)n*H + h] = fmaf(vdot[(size_t)n*H + h], o2, o3);
    #pragma unroll
    for (int l = 0; l < LD; l++){
        size_t i2 = ((size_t)n*LD + l)*H + h;
        dvec[i2] = fmaf(vec3[i2], o1, av[l]);
    }
}

// ---------------------------------------------------------------------------
extern "C" void kernel_launch(void* const* d_in, const int* in_sizes, int n_in,
                              void* d_out, int out_size, void* d_ws, size_t ws_size,
                              hipStream_t stream) {
    const float* nf    = (const float*)d_in[0];
    const float* ef    = (const float*)d_in[1];
    const float* vf    = (const float*)d_in[2];
    const float* dist  = (const float*)d_in[3];
    const float* dij   = (const float*)d_in[4];
    const int*   snd   = (const int*)d_in[5];
    const int*   rcv   = (const int*)d_in[6];
    const float* ln_s  = (const float*)d_in[7];
    const float* ln_b  = (const float*)d_in[8];
    const float* vlnw  = (const float*)d_in[9];
    const float* W_vec = (const float*)d_in[10];
    const float* Wq    = (const float*)d_in[11];
    const float* bq    = (const float*)d_in[12];
    const float* Wk    = (const float*)d_in[13];
    const float* bk    = (const float*)d_in[14];
    const float* Wv    = (const float*)d_in[15];
    const float* bv    = (const float*)d_in[16];
    const float* Wdk   = (const float*)d_in[17];
    const float* bdk   = (const float*)d_in[18];
    const float* Wdv   = (const float*)d_in[19];
    const float* bdv   = (const float*)d_in[20];
    const float* Ws    = (const float*)d_in[21];
    const float* bs    = (const float*)d_in[22];
    const float* Wo    = (const float*)d_in[23];
    const float* bo    = (const float*)d_in[24];
    const float* Wf    = (const float*)d_in[25];
    const float* bf_   = (const float*)d_in[26];
    const float* Wsrc  = (const float*)d_in[27];
    const float* Wtrg  = (const float*)d_in[28];

    float* out  = (float*)d_out;
    float* dx   = out;                                  // [NN, H]
    float* df   = out + (size_t)NN*H;                   // [NE, H]
    float* dvec = df + (size_t)NE*H;                    // [NN, LD, H]

    float* w = (float*)d_ws;
    size_t off = 0;
    float* q    = w + off; off += (size_t)NN*H;
    float* k    = w + off; off += (size_t)NN*H;
    float* v    = w + off; off += (size_t)NN*H;
    float* vdot = w + off; off += (size_t)NN*H;
    float* vec3 = w + off; off += (size_t)NN*LD*H;
    ushort_t* vec_bf = (ushort_t*)(w + off); off += (size_t)NN*LD*H/2;
    ushort_t* Vt     = (ushort_t*)(w + off); off += (size_t)NN*LD*H/2;
    ushort_t* Vs     = (ushort_t*)(w + off); off += (size_t)NN*LD*H/2;
    ushort_t* vj     = (ushort_t*)(w + off); off += (size_t)NE*H/2;
    ushort_t* s12    = (ushort_t*)(w + off); off += (size_t)NE*256/2;
    int* cnt  = (int*)(w + off); off += NN;
    int* cnt2 = (int*)(w + off); off += NN;
    int* offs = (int*)(w + off); off += NN + 1;
    int* eidx = (int*)(w + off); off += NE;

    hipMemsetAsync(cnt,  0, NN*sizeof(int), stream);
    hipMemsetAsync(cnt2, 0, NN*sizeof(int), stream);

    k_hist<<<(NE+255)/256, 256, 0, stream>>>(rcv, cnt);
    k_scan<<<1, 256, 0, stream>>>(cnt, offs);
    k_scatter<<<(NE+255)/256, 256, 0, stream>>>(rcv, offs, cnt2, eidx);

    node_pre<<<NN, 128, 0, stream>>>(nf, vf, ln_s, ln_b, vlnw, W_vec,
                                     Wq, bq, Wk, bk, Wv, bv, Wtrg, Wsrc,
                                     q, k, v, vec_bf, vdot, vec3, Vt, Vs);

    edge_attn<<<dim3(NE/32, 2), 256, 0, stream>>>(ef, Wdk, bdk, Wdv, bdv, snd, rcv, dist,
                                                  q, k, v, vj);

    edge_df<<<dim3(NE/16, 2), 256, 0, stream>>>(ef, Wf, bf_, eidx, snd, rcv, dij, Vt, Vs, df);

    edge_s<<<dim3(NE/32, 2), 256, 0, stream>>>(vj, Ws, bs, s12);

    node_gather<<<NN, 128, 0, stream>>>(offs, eidx, snd, vj, s12, dij, vec_bf,
                                        Wo, bo, vdot, vec3, dx, dvec);
}

// Round 5
// 910.714 us; speedup vs baseline: 3.5542x; 1.1452x over previous
//
#include <hip/hip_runtime.h>
#include <math.h>

#define NN 10000
#define NE 160000
#define H  128
#define LD 8

typedef unsigned short ushort_t;
typedef short bf16x8 __attribute__((ext_vector_type(8)));
typedef float f32x4 __attribute__((ext_vector_type(4)));

__device__ __forceinline__ float silu_f(float x){ return x / (1.0f + expf(-x)); }
__device__ __forceinline__ float4 f4z(){ return make_float4(0.f,0.f,0.f,0.f); }

__device__ __forceinline__ void fma4(float4& acc, float s, const float4 w){
    acc.x = fmaf(s, w.x, acc.x);
    acc.y = fmaf(s, w.y, acc.y);
    acc.z = fmaf(s, w.z, acc.z);
    acc.w = fmaf(s, w.w, acc.w);
}

__device__ __forceinline__ float4 silu4(float4 a, float4 b){
    return make_float4(silu_f(a.x+b.x), silu_f(a.y+b.y), silu_f(a.z+b.z), silu_f(a.w+b.w));
}

__device__ __forceinline__ ushort_t f2bf(float f){
    union { float f; unsigned int u; } x; x.f = f;
    unsigned int r = x.u + 0x7FFFu + ((x.u >> 16) & 1u);
    return (ushort_t)(r >> 16);
}
__device__ __forceinline__ unsigned int pack2bf(float a, float b){
    return (unsigned int)f2bf(a) | ((unsigned int)f2bf(b) << 16);
}
__device__ __forceinline__ float bf2f_hi(unsigned int u){
    union { unsigned int u; float f; } x; x.u = u & 0xffff0000u; return x.f;
}
__device__ __forceinline__ float bf2f_lo(unsigned int u){
    union { unsigned int u; float f; } x; x.u = u << 16; return x.f;
}

// ---------------------------------------------------------------------------
// Prep: transpose weights to bf16 W^T[n][k]; cast ef to bf16.
// ---------------------------------------------------------------------------
__global__ void k_prepw(const float* __restrict__ Wdk, const float* __restrict__ Wdv,
                        const float* __restrict__ Ws,
                        ushort_t* __restrict__ wdkT, ushort_t* __restrict__ wdvT,
                        ushort_t* __restrict__ wsT){
    int i = blockIdx.x * 256 + threadIdx.x;          // 0 .. 32767
    if (i < 128*128){
        int n = i >> 7, kk = i & 127;
        wdkT[n*128 + kk] = f2bf(Wdk[kk*128 + n]);
        wdvT[n*128 + kk] = f2bf(Wdv[kk*128 + n]);
    }
    if (i < 256*128){
        int n = i >> 7, kk = i & 127;                // n in [0,256)
        wsT[n*128 + kk] = f2bf(Ws[kk*256 + n]);
    }
}

__global__ void k_ef2bf(const float* __restrict__ ef, ushort_t* __restrict__ ef_bf){
    size_t i = (size_t)blockIdx.x * 256 + threadIdx.x;   // over E*H/8
    const float4* s = (const float4*)ef;
    float4 a = s[2*i], b = s[2*i+1];
    uint4 u;
    u.x = pack2bf(a.x, a.y); u.y = pack2bf(a.z, a.w);
    u.z = pack2bf(b.x, b.y); u.w = pack2bf(b.z, b.w);
    ((uint4*)ef_bf)[i] = u;
}

// ---------------------------------------------------------------------------
// Sort edges by receiver: histogram -> exclusive scan -> rank scatter.
// ---------------------------------------------------------------------------
__global__ void k_hist(const int* __restrict__ rcv, int* __restrict__ cnt){
    int e = blockIdx.x * 256 + threadIdx.x;
    if (e < NE) atomicAdd(&cnt[rcv[e]], 1);
}

__global__ __launch_bounds__(256) void k_scan(const int* __restrict__ cnt, int* __restrict__ offs){
    __shared__ int part[256];
    const int t = threadIdx.x;
    const int CH = 40;
    int loc[CH];
    int base = t * CH;
    int lsum = 0;
    if (base < NN){
        #pragma unroll
        for (int i = 0; i < CH; i++){ loc[i] = cnt[base + i]; lsum += loc[i]; }
    }
    part[t] = lsum;
    __syncthreads();
    for (int off = 1; off < 256; off <<= 1){
        int v = (t >= off) ? part[t - off] : 0;
        __syncthreads();
        part[t] += v;
        __syncthreads();
    }
    int ex = part[t] - lsum;
    if (base < NN){
        int run = ex;
        #pragma unroll
        for (int i = 0; i < CH; i++){ offs[base + i] = run; run += loc[i]; }
    }
    if (t == 255) offs[NN] = part[255];
}

__global__ void k_scatter(const int* __restrict__ rcv, const int* __restrict__ offs,
                          int* __restrict__ cnt2, int* __restrict__ eidx){
    int e = blockIdx.x * 256 + threadIdx.x;
    if (e < NE){
        int r = rcv[e];
        int p = atomicAdd(&cnt2[r], 1);
        eidx[offs[r] + p] = e;
    }
}

// ---------------------------------------------------------------------------
// K1: per-node: LayerNorm; q,k,v; vec (bf16); vec_dot, vec3; Vt/Vs (bf16).
// ---------------------------------------------------------------------------
__global__ __launch_bounds__(128) void node_pre(
    const float* __restrict__ nf, const float* __restrict__ vf,
    const float* __restrict__ ln_s, const float* __restrict__ ln_b,
    const float* __restrict__ vlnw, const float* __restrict__ W_vec,
    const float* __restrict__ Wq, const float* __restrict__ bq,
    const float* __restrict__ Wk, const float* __restrict__ bk,
    const float* __restrict__ Wv, const float* __restrict__ bv,
    const float* __restrict__ Wtrg, const float* __restrict__ Wsrc,
    float* __restrict__ q, float* __restrict__ k, float* __restrict__ v,
    ushort_t* __restrict__ vec_bf, float* __restrict__ vdot, float* __restrict__ vec3,
    ushort_t* __restrict__ Vt, ushort_t* __restrict__ Vs)
{
    const int n = blockIdx.x;
    const int h = threadIdx.x;
    __shared__ float x_s[H];
    __shared__ float vec_s[LD][H];
    __shared__ float red[4];

    float xv = nf[(size_t)n*H + h];
    float s1 = xv, s2 = xv*xv;
    #pragma unroll
    for (int o = 32; o >= 1; o >>= 1){
        s1 += __shfl_xor(s1, o, 64);
        s2 += __shfl_xor(s2, o, 64);
    }
    const int wid = h >> 6;
    if ((h & 63) == 0){ red[wid] = s1; red[2+wid] = s2; }
    __syncthreads();
    float mean = (red[0] + red[1]) * (1.0f/H);
    float var  = (red[2] + red[3]) * (1.0f/H) - mean*mean;
    float x = (xv - mean) * rsqrtf(var + 1e-5f) * ln_s[h] + ln_b[h];
    x_s[h] = x;
    float w = vlnw[h];
    #pragma unroll
    for (int l = 0; l < LD; l++){
        size_t i = ((size_t)n*LD + l)*H + h;
        float t = vf[i] * w;
        vec_s[l][h] = t;
        vec_bf[i] = f2bf(t);
    }
    __syncthreads();

    float aq = bq[h], ak = bk[h], av = bv[h];
    float a1[LD], a2[LD], a3[LD], at[LD], as_[LD];
    #pragma unroll
    for (int l = 0; l < LD; l++){ a1[l]=0.f; a2[l]=0.f; a3[l]=0.f; at[l]=0.f; as_[l]=0.f; }

    for (int kk = 0; kk < H; kk++){
        float xk = x_s[kk];
        aq = fmaf(xk, Wq[kk*H + h], aq);
        ak = fmaf(xk, Wk[kk*H + h], ak);
        av = fmaf(xk, Wv[kk*H + h], av);
        float w1 = W_vec[kk*(3*H) + h];
        float w2 = W_vec[kk*(3*H) + H + h];
        float w3 = W_vec[kk*(3*H) + 2*H + h];
        float wt = Wtrg[kk*H + h];
        float ws = Wsrc[kk*H + h];
        #pragma unroll
        for (int l = 0; l < LD; l++){
            float vk = vec_s[l][kk];
            a1[l] = fmaf(vk, w1, a1[l]);
            a2[l] = fmaf(vk, w2, a2[l]);
            a3[l] = fmaf(vk, w3, a3[l]);
            at[l] = fmaf(vk, wt, at[l]);
            as_[l]= fmaf(vk, ws, as_[l]);
        }
    }
    q[(size_t)n*H + h] = aq;
    k[(size_t)n*H + h] = ak;
    v[(size_t)n*H + h] = av;
    float vd = 0.f;
    #pragma unroll
    for (int l = 0; l < LD; l++) vd = fmaf(a1[l], a2[l], vd);
    vdot[(size_t)n*H + h] = vd;
    #pragma unroll
    for (int l = 0; l < LD; l++){
        size_t i = ((size_t)n*LD + l)*H + h;
        vec3[i] = a3[l];
        Vt[i]   = f2bf(at[l]);
        Vs[i]   = f2bf(as_[l]);
    }
}

// ---------------------------------------------------------------------------
// K2 (MFMA): dk/dv = silu(ef@Wdk/dv + b) via mfma_16x16x32_bf16, then
// attention epilogue -> vj (bf16). 64 edges/block, 4 waves x 16-row stripe.
// ---------------------------------------------------------------------------
__global__ __launch_bounds__(256) void edge_attn(
    const ushort_t* __restrict__ ef_bf,
    const ushort_t* __restrict__ wdkT, const float* __restrict__ bdk,
    const ushort_t* __restrict__ wdvT, const float* __restrict__ bdv,
    const int* __restrict__ snd, const int* __restrict__ rcv,
    const float* __restrict__ dist,
    const float* __restrict__ q, const float* __restrict__ k, const float* __restrict__ v,
    ushort_t* __restrict__ vj)
{
    __shared__ ushort_t dk_s[64][136];
    __shared__ ushort_t dv_s[64][136];

    const int tid  = threadIdx.x;
    const int lane = tid & 63;
    const int m0   = (tid >> 6) * 16;           // wave's row stripe
    const size_t e0 = (size_t)blockIdx.x * 64;

    const int mrow = lane & 15;
    const int kblk = lane >> 4;

    f32x4 accK[8], accV[8];
    #pragma unroll
    for (int nt = 0; nt < 8; nt++){ accK[nt] = (f32x4)(0.f); accV[nt] = (f32x4)(0.f); }

    const ushort_t* Arow = ef_bf + (e0 + m0 + mrow)*H + kblk*8;
    const ushort_t* wkb  = wdkT + (size_t)mrow*H + kblk*8;
    const ushort_t* wvb  = wdvT + (size_t)mrow*H + kblk*8;

    #pragma unroll
    for (int ks = 0; ks < 4; ks++){
        bf16x8 a = *(const bf16x8*)(Arow + ks*32);
        #pragma unroll
        for (int nt = 0; nt < 8; nt++){
            bf16x8 bk8 = *(const bf16x8*)(wkb + (size_t)nt*16*H + ks*32);
            accK[nt] = __builtin_amdgcn_mfma_f32_16x16x32_bf16(a, bk8, accK[nt], 0, 0, 0);
            bf16x8 bv8 = *(const bf16x8*)(wvb + (size_t)nt*16*H + ks*32);
            accV[nt] = __builtin_amdgcn_mfma_f32_16x16x32_bf16(a, bv8, accV[nt], 0, 0, 0);
        }
    }

    const int lrow = m0 + 4*kblk;
    #pragma unroll
    for (int nt = 0; nt < 8; nt++){
        int coln = nt*16 + mrow;
        float bkn = bdk[coln], bvn = bdv[coln];
        #pragma unroll
        for (int r = 0; r < 4; r++){
            dk_s[lrow + r][coln] = f2bf(silu_f(accK[nt][r] + bkn));
            dv_s[lrow + r][coln] = f2bf(silu_f(accV[nt][r] + bvn));
        }
    }
    __syncthreads();

    // epilogue: thread t -> edge row r, 32-col quarter cq
    const int r  = tid >> 2, cq = tid & 3;
    const size_t e = e0 + r;
    const int s  = snd[e], rr = rcv[e];
    const float d = dist[e];
    const float cut = (d < 5.0f) ? 0.5f*(cosf(d*0.6283185307179586f) + 1.0f) : 0.0f;
    const float* qrow = q + (size_t)rr*H + cq*32;
    const float* krow = k + (size_t)s*H + cq*32;
    const float* vrow = v + (size_t)s*H + cq*32;
    ushort_t* vjrow = vj + e*H + cq*32;

    #pragma unroll
    for (int hh = 0; hh < 2; hh++){
        const int c0 = hh*16;
        float p = 0.f;
        #pragma unroll
        for (int j = 0; j < 4; j++){
            float4 q4 = *(const float4*)(qrow + c0 + 4*j);
            float4 k4 = *(const float4*)(krow + c0 + 4*j);
            uint2 du = *(const uint2*)&dk_s[r][cq*32 + c0 + 4*j];
            p += q4.x*k4.x*bf2f_lo(du.x) + q4.y*k4.y*bf2f_hi(du.x)
               + q4.z*k4.z*bf2f_lo(du.y) + q4.w*k4.w*bf2f_hi(du.y);
        }
        float attn = silu_f(p) * cut;
        #pragma unroll
        for (int j = 0; j < 4; j++){
            float4 v4 = *(const float4*)(vrow + c0 + 4*j);
            uint2 du = *(const uint2*)&dv_s[r][cq*32 + c0 + 4*j];
            uint2 u;
            u.x = pack2bf(v4.x*bf2f_lo(du.x)*attn, v4.y*bf2f_hi(du.x)*attn);
            u.y = pack2bf(v4.z*bf2f_lo(du.y)*attn, v4.w*bf2f_hi(du.y)*attn);
            *(uint2*)(vjrow + c0 + 4*j) = u;
        }
    }
}

// ---------------------------------------------------------------------------
// K3 (MFMA): s12 = silu(vj@Ws + bs) [E,256] bf16. 64 edges/block.
// ---------------------------------------------------------------------------
__global__ __launch_bounds__(256) void edge_s(
    const ushort_t* __restrict__ vj, const ushort_t* __restrict__ wsT,
    const float* __restrict__ bs, ushort_t* __restrict__ s12)
{
    __shared__ ushort_t s_s[64][264];

    const int tid  = threadIdx.x;
    const int lane = tid & 63;
    const int m0   = (tid >> 6) * 16;
    const size_t e0 = (size_t)blockIdx.x * 64;

    const int mrow = lane & 15;
    const int kblk = lane >> 4;

    f32x4 acc[16];
    #pragma unroll
    for (int nt = 0; nt < 16; nt++) acc[nt] = (f32x4)(0.f);

    const ushort_t* Arow = vj + (e0 + m0 + mrow)*H + kblk*8;
    const ushort_t* wb   = wsT + (size_t)mrow*H + kblk*8;

    #pragma unroll
    for (int ks = 0; ks < 4; ks++){
        bf16x8 a = *(const bf16x8*)(Arow + ks*32);
        #pragma unroll
        for (int nt = 0; nt < 16; nt++){
            bf16x8 b8 = *(const bf16x8*)(wb + (size_t)nt*16*H + ks*32);
            acc[nt] = __builtin_amdgcn_mfma_f32_16x16x32_bf16(a, b8, acc[nt], 0, 0, 0);
        }
    }

    const int lrow = m0 + 4*kblk;
    #pragma unroll
    for (int nt = 0; nt < 16; nt++){
        int coln = nt*16 + mrow;
        float bb = bs[coln];
        #pragma unroll
        for (int r = 0; r < 4; r++)
            s_s[lrow + r][coln] = f2bf(silu_f(acc[nt][r] + bb));
    }
    __syncthreads();

    const int r = tid >> 2, cq = tid & 3;
    const uint4* srcp = (const uint4*)&s_s[r][cq*64];
    uint4* dstp = (uint4*)&s12[(e0 + r)*256 + cq*64];
    #pragma unroll
    for (int j = 0; j < 8; j++) dstp[j] = srcp[j];
}

// ---------------------------------------------------------------------------
// K4 (f32 GEMV — precision-critical): df_ij = silu(ef@Wf+bf) * w_dot with
// w_dot = (A.B) - a*b*(2 - |d|^2), A = Vt[rcv] (bf16), B = Vs[snd] (bf16).
// f stays in f32 end-to-end (w_dot tails reach ~1e3; bf16 f fails threshold).
// Receiver-sorted edge order; column-half split per blockIdx.y.
// ---------------------------------------------------------------------------
__global__ __launch_bounds__(256) void edge_df(
    const float* __restrict__ ef, const float* __restrict__ Wf, const float* __restrict__ bf_,
    const int* __restrict__ eidx,
    const int* __restrict__ snd, const int* __restrict__ rcv,
    const float* __restrict__ dij,
    const ushort_t* __restrict__ Vt, const ushort_t* __restrict__ Vs,
    float* __restrict__ df)
{
    __shared__ float wf_s[H][64];
    __shared__ float e_s[16][H];
    __shared__ int   eidx_s[16];
    __shared__ int   snd_s[16];
    __shared__ int   rcv_s[16];
    __shared__ float dij_s[16][LD];

    const int tid = threadIdx.x;
    const int by = blockIdx.y;
    const int p0 = blockIdx.x * 16;      // sorted positions [p0, p0+16)

    if (tid < 16) eidx_s[tid] = eidx[p0 + tid];
    __syncthreads();

    for (int i = tid; i < H*16; i += 256){          // Wf half: 128 rows x 16 f4
        int row = i >> 4, c4 = i & 15;
        *(float4*)&wf_s[row][c4*4] = *(const float4*)&Wf[row*H + by*64 + c4*4];
    }
    for (int i = tid; i < 16*32; i += 256){         // 16 rows x 32 float4
        int row = i >> 5, c4 = i & 31;
        *(float4*)&e_s[row][c4*4] = *(const float4*)&ef[(size_t)eidx_s[row]*H + c4*4];
    }
    if (tid < 16){ snd_s[tid] = snd[eidx_s[tid]]; rcv_s[tid] = rcv[eidx_s[tid]]; }
    if (tid < 16*LD){
        int row = tid >> 3, l = tid & 7;
        dij_s[row][l] = dij[(size_t)eidx_s[row]*LD + l];
    }
    __syncthreads();

    const int g = tid & 15, r0 = tid >> 4;          // 16 cols-of-4, 16 rows
    float4 af = f4z();
    for (int kk = 0; kk < H; kk++){
        float4 w4 = *(float4*)&wf_s[kk][g*4];
        fma4(af, e_s[r0][kk], w4);
    }
    float4 bf4 = *(const float4*)&bf_[by*64 + g*4];
    float4 f4 = silu4(af, bf4);

    const int e = eidx_s[r0];
    const int s = snd_s[r0], rr = rcv_s[r0];
    const ushort_t* Ar = Vt + ((size_t)rr*LD)*H + by*64 + g*4;
    const ushort_t* Br = Vs + ((size_t)s*LD)*H + by*64 + g*4;

    float4 AB = f4z(), aa = f4z(), bb = f4z();
    float dd = 0.f;
    #pragma unroll
    for (int l = 0; l < LD; l++){
        float dl = dij_s[r0][l];
        dd = fmaf(dl, dl, dd);
        uint2 ua = *(const uint2*)&Ar[(size_t)l*H];
        uint2 ub = *(const uint2*)&Br[(size_t)l*H];
        float Ax = bf2f_lo(ua.x), Ay = bf2f_hi(ua.x), Az = bf2f_lo(ua.y), Aw = bf2f_hi(ua.y);
        float Bx = bf2f_lo(ub.x), By = bf2f_hi(ub.x), Bz = bf2f_lo(ub.y), Bw = bf2f_hi(ub.y);
        AB.x = fmaf(Ax, Bx, AB.x); AB.y = fmaf(Ay, By, AB.y);
        AB.z = fmaf(Az, Bz, AB.z); AB.w = fmaf(Aw, Bw, AB.w);
        aa.x = fmaf(Ax, dl, aa.x); aa.y = fmaf(Ay, dl, aa.y);
        aa.z = fmaf(Az, dl, aa.z); aa.w = fmaf(Aw, dl, aa.w);
        bb.x = fmaf(Bx, dl, bb.x); bb.y = fmaf(By, dl, bb.y);
        bb.z = fmaf(Bz, dl, bb.z); bb.w = fmaf(Bw, dl, bb.w);
    }
    float c = 2.0f - dd;
    float4 o = make_float4(f4.x*(AB.x - aa.x*bb.x*c),
                           f4.y*(AB.y - aa.y*bb.y*c),
                           f4.z*(AB.z - aa.z*bb.z*c),
                           f4.w*(AB.w - aa.w*bb.w*c));
    *(float4*)&df[(size_t)e*H + by*64 + g*4] = o;
}

// ---------------------------------------------------------------------------
// K5: per-receiver gather + fused node_post.
// ---------------------------------------------------------------------------
__global__ __launch_bounds__(128) void node_gather(
    const int* __restrict__ offs, const int* __restrict__ eidx, const int* __restrict__ snd,
    const ushort_t* __restrict__ vj, const ushort_t* __restrict__ s12,
    const float* __restrict__ dij, const ushort_t* __restrict__ vec,
    const float* __restrict__ Wo, const float* __restrict__ bo,
    const float* __restrict__ vdot, const float* __restrict__ vec3,
    float* __restrict__ dx, float* __restrict__ dvec)
{
    const int n = blockIdx.x, h = threadIdx.x;
    const int beg = offs[n], end = offs[n+1];
    float na = 0.f;
    float av[LD];
    #pragma unroll
    for (int l = 0; l < LD; l++) av[l] = 0.f;

    for (int i = beg; i < end; i++){
        int e = eidx[i];
        int s = snd[e];
        float vjv = bf2f_lo((unsigned int)vj[(size_t)e*H + h]);
        float s1 = bf2f_lo((unsigned int)s12[(size_t)e*256 + h]);
        float s2 = bf2f_lo((unsigned int)s12[(size_t)e*256 + 128 + h]);
        na += vjv;
        float4 d0 = *(const float4*)&dij[(size_t)e*LD];
        float4 d1 = *(const float4*)&dij[(size_t)e*LD + 4];
        const ushort_t* vr = &vec[(size_t)s*LD*H + h];
        av[0] = fmaf(bf2f_lo((unsigned int)vr[0*H]), s1, fmaf(d0.x, s2, av[0]));
        av[1] = fmaf(bf2f_lo((unsigned int)vr[1*H]), s1, fmaf(d0.y, s2, av[1]));
        av[2] = fmaf(bf2f_lo((unsigned int)vr[2*H]), s1, fmaf(d0.z, s2, av[2]));
        av[3] = fmaf(bf2f_lo((unsigned int)vr[3*H]), s1, fmaf(d0.w, s2, av[3]));
        av[4] = fmaf(bf2f_lo((unsigned int)vr[4*H]), s1, fmaf(d1.x, s2, av[4]));
        av[5] = fmaf(bf2f_lo((unsigned int)vr[5*H]), s1, fmaf(d1.y, s2, av[5]));
        av[6] = fmaf(bf2f_lo((unsigned int)vr[6*H]), s1, fmaf(d1.z, s2, av[6]));
        av[7] = fmaf(bf2f_lo((unsigned int)vr[7*H]), s1, fmaf(d1.w, s2, av[7]));
    }

    __shared__ float na_s[H];
    na_s[h] = na;
    __syncthreads();
    float o1 = bo[h], o2 = bo[H + h], o3 = bo[2*H + h];
    for (int kk = 0; kk < H; kk++){
        float a = na_s[kk];
        o1 = fmaf(a, Wo[kk*(3*H) + h], o1);
        o2 = fmaf(a, Wo[kk*(3*H) + H + h], o2);
        o3 = fmaf(a, Wo[kk*(3*H) + 2*H + h], o3);
    }
    dx[(size_t)n*H + h] = fmaf(vdot[(size_t)n*H + h], o2, o3);
    #pragma unroll
    for (int l = 0; l < LD; l++){
        size_t i2 = ((size_t)n*LD + l)*H + h;
        dvec[i2] = fmaf(vec3[i2], o1, av[l]);
    }
}

// ---------------------------------------------------------------------------
extern "C" void kernel_launch(void* const* d_in, const int* in_sizes, int n_in,
                              void* d_out, int out_size, void* d_ws, size_t ws_size,
                              hipStream_t stream) {
    const float* nf    = (const float*)d_in[0];
    const float* ef    = (const float*)d_in[1];
    const float* vf    = (const float*)d_in[2];
    const float* dist  = (const float*)d_in[3];
    const float* dij   = (const float*)d_in[4];
    const int*   snd   = (const int*)d_in[5];
    const int*   rcv   = (const int*)d_in[6];
    const float* ln_s  = (const float*)d_in[7];
    const float* ln_b  = (const float*)d_in[8];
    const float* vlnw  = (const float*)d_in[9];
    const float* W_vec = (const float*)d_in[10];
    const float* Wq    = (const float*)d_in[11];
    const float* bq    = (const float*)d_in[12];
    const float* Wk    = (const float*)d_in[13];
    const float* bk    = (const float*)d_in[14];
    const float* Wv    = (const float*)d_in[15];
    const float* bv    = (const float*)d_in[16];
    const float* Wdk   = (const float*)d_in[17];
    const float* bdk   = (const float*)d_in[18];
    const float* Wdv   = (const float*)d_in[19];
    const float* bdv   = (const float*)d_in[20];
    const float* Ws    = (const float*)d_in[21];
    const float* bs    = (const float*)d_in[22];
    const float* Wo    = (const float*)d_in[23];
    const float* bo    = (const float*)d_in[24];
    const float* Wf    = (const float*)d_in[25];
    const float* bf_   = (const float*)d_in[26];
    const float* Wsrc  = (const float*)d_in[27];
    const float* Wtrg  = (const float*)d_in[28];

    float* out  = (float*)d_out;
    float* dx   = out;                                  // [NN, H]
    float* df   = out + (size_t)NN*H;                   // [NE, H]
    float* dvec = df + (size_t)NE*H;                    // [NN, LD, H]

    float* w = (float*)d_ws;
    size_t off = 0;
    float* q    = w + off; off += (size_t)NN*H;
    float* k    = w + off; off += (size_t)NN*H;
    float* v    = w + off; off += (size_t)NN*H;
    float* vdot = w + off; off += (size_t)NN*H;
    float* vec3 = w + off; off += (size_t)NN*LD*H;
    ushort_t* vec_bf = (ushort_t*)(w + off); off += (size_t)NN*LD*H/2;
    ushort_t* Vt     = (ushort_t*)(w + off); off += (size_t)NN*LD*H/2;
    ushort_t* Vs     = (ushort_t*)(w + off); off += (size_t)NN*LD*H/2;
    ushort_t* vj     = (ushort_t*)(w + off); off += (size_t)NE*H/2;
    // s12 [E,256] bf16 aliases ef_bf [E,128] bf16 (ef_bf dead after edge_attn;
    // edge_s writes s12 afterwards).
    ushort_t* s12    = (ushort_t*)(w + off); off += (size_t)NE*256/2;
    ushort_t* ef_bf  = s12;
    ushort_t* wdkT = (ushort_t*)(w + off); off += 128*128/2;
    ushort_t* wdvT = (ushort_t*)(w + off); off += 128*128/2;
    ushort_t* wsT  = (ushort_t*)(w + off); off += 256*128/2;
    int* cnt  = (int*)(w + off); off += NN;
    int* cnt2 = (int*)(w + off); off += NN;
    int* offs = (int*)(w + off); off += NN + 1;
    int* eidx = (int*)(w + off); off += NE;

    hipMemsetAsync(cnt,  0, NN*sizeof(int), stream);
    hipMemsetAsync(cnt2, 0, NN*sizeof(int), stream);

    k_prepw<<<128, 256, 0, stream>>>(Wdk, Wdv, Ws, wdkT, wdvT, wsT);
    k_ef2bf<<<NE*H/8/256, 256, 0, stream>>>(ef, ef_bf);

    k_hist<<<(NE+255)/256, 256, 0, stream>>>(rcv, cnt);
    k_scan<<<1, 256, 0, stream>>>(cnt, offs);
    k_scatter<<<(NE+255)/256, 256, 0, stream>>>(rcv, offs, cnt2, eidx);

    node_pre<<<NN, 128, 0, stream>>>(nf, vf, ln_s, ln_b, vlnw, W_vec,
                                     Wq, bq, Wk, bk, Wv, bv, Wtrg, Wsrc,
                                     q, k, v, vec_bf, vdot, vec3, Vt, Vs);

    edge_attn<<<NE/64, 256, 0, stream>>>(ef_bf, wdkT, bdk, wdvT, bdv, snd, rcv, dist,
                                         q, k, v, vj);

    edge_df<<<dim3(NE/16, 2), 256, 0, stream>>>(ef, Wf, bf_, eidx, snd, rcv, dij, Vt, Vs, df);

    edge_s<<<NE/64, 256, 0, stream>>>(vj, wsT, bs, s12);

    node_gather<<<NN, 128, 0, stream>>>(offs, eidx, snd, vj, s12, dij, vec_bf,
                                        Wo, bo, vdot, vec3, dx, dvec);
}

// Round 6
// 838.306 us; speedup vs baseline: 3.8612x; 1.0864x over previous
//
#include <hip/hip_runtime.h>
#include <math.h>

#define NN 10000
#define NE 160000
#define H  128
#define LD 8

typedef unsigned short ushort_t;
typedef short bf16x8 __attribute__((ext_vector_type(8)));
typedef float f32x4 __attribute__((ext_vector_type(4)));

__device__ __forceinline__ float silu_f(float x){ return x / (1.0f + expf(-x)); }
__device__ __forceinline__ float4 f4z(){ return make_float4(0.f,0.f,0.f,0.f); }

__device__ __forceinline__ void fma4(float4& acc, float s, const float4 w){
    acc.x = fmaf(s, w.x, acc.x);
    acc.y = fmaf(s, w.y, acc.y);
    acc.z = fmaf(s, w.z, acc.z);
    acc.w = fmaf(s, w.w, acc.w);
}

__device__ __forceinline__ float4 silu4(float4 a, float4 b){
    return make_float4(silu_f(a.x+b.x), silu_f(a.y+b.y), silu_f(a.z+b.z), silu_f(a.w+b.w));
}

__device__ __forceinline__ ushort_t f2bf(float f){
    union { float f; unsigned int u; } x; x.f = f;
    unsigned int r = x.u + 0x7FFFu + ((x.u >> 16) & 1u);
    return (ushort_t)(r >> 16);
}
__device__ __forceinline__ unsigned int pack2bf(float a, float b){
    return (unsigned int)f2bf(a) | ((unsigned int)f2bf(b) << 16);
}
__device__ __forceinline__ float bf2f_hi(unsigned int u){
    union { unsigned int u; float f; } x; x.u = u & 0xffff0000u; return x.f;
}
__device__ __forceinline__ float bf2f_lo(unsigned int u){
    union { unsigned int u; float f; } x; x.u = u << 16; return x.f;
}

// ---------------------------------------------------------------------------
// Prep: transpose all GEMM weights to bf16 W^T[n][k]; cast ef to bf16.
// wqkvT: [384,128] = [Wq|Wk|Wv]^T; wvecT: [640,128] = [W1|W2|W3|Wtrg|Wsrc]^T.
// ---------------------------------------------------------------------------
__global__ void k_prepw(const float* __restrict__ Wq, const float* __restrict__ Wk,
                        const float* __restrict__ Wv, const float* __restrict__ W_vec,
                        const float* __restrict__ Wtrg, const float* __restrict__ Wsrc,
                        const float* __restrict__ Wdk, const float* __restrict__ Wdv,
                        const float* __restrict__ Ws,
                        ushort_t* __restrict__ wqkvT, ushort_t* __restrict__ wvecT,
                        ushort_t* __restrict__ wdkT, ushort_t* __restrict__ wdvT,
                        ushort_t* __restrict__ wsT){
    int i = blockIdx.x * 256 + threadIdx.x;          // 0 .. 196607
    int n = i >> 7, kk = i & 127;
    if (n < 384){                                    // wqkvT
        float v;
        if (n < 128)      v = Wq[kk*128 + n];
        else if (n < 256) v = Wk[kk*128 + (n-128)];
        else              v = Wv[kk*128 + (n-256)];
        wqkvT[n*128 + kk] = f2bf(v);
    } else if (n < 1024){                            // wvecT (640 rows)
        int m = n - 384;
        float v;
        if (m < 384)      v = W_vec[kk*384 + m];
        else if (m < 512) v = Wtrg[kk*128 + (m-384)];
        else              v = Wsrc[kk*128 + (m-512)];
        wvecT[m*128 + kk] = f2bf(v);
    } else if (n < 1152){
        int m = n - 1024;
        wdkT[m*128 + kk] = f2bf(Wdk[kk*128 + m]);
    } else if (n < 1280){
        int m = n - 1152;
        wdvT[m*128 + kk] = f2bf(Wdv[kk*128 + m]);
    } else if (n < 1536){
        int m = n - 1280;
        wsT[m*128 + kk] = f2bf(Ws[kk*256 + m]);
    }
}

__global__ void k_ef2bf(const float* __restrict__ ef, ushort_t* __restrict__ ef_bf){
    size_t i = (size_t)blockIdx.x * 256 + threadIdx.x;   // over E*H/8
    const float4* s = (const float4*)ef;
    float4 a = s[2*i], b = s[2*i+1];
    uint4 u;
    u.x = pack2bf(a.x, a.y); u.y = pack2bf(a.z, a.w);
    u.z = pack2bf(b.x, b.y); u.w = pack2bf(b.z, b.w);
    ((uint4*)ef_bf)[i] = u;
}

// ---------------------------------------------------------------------------
// Sort edges by receiver: histogram -> exclusive scan -> rank scatter.
// ---------------------------------------------------------------------------
__global__ void k_hist(const int* __restrict__ rcv, int* __restrict__ cnt){
    int e = blockIdx.x * 256 + threadIdx.x;
    if (e < NE) atomicAdd(&cnt[rcv[e]], 1);
}

__global__ __launch_bounds__(256) void k_scan(const int* __restrict__ cnt, int* __restrict__ offs){
    __shared__ int part[256];
    const int t = threadIdx.x;
    const int CH = 40;
    int loc[CH];
    int base = t * CH;
    int lsum = 0;
    if (base < NN){
        #pragma unroll
        for (int i = 0; i < CH; i++){ loc[i] = cnt[base + i]; lsum += loc[i]; }
    }
    part[t] = lsum;
    __syncthreads();
    for (int off = 1; off < 256; off <<= 1){
        int v = (t >= off) ? part[t - off] : 0;
        __syncthreads();
        part[t] += v;
        __syncthreads();
    }
    int ex = part[t] - lsum;
    if (base < NN){
        int run = ex;
        #pragma unroll
        for (int i = 0; i < CH; i++){ offs[base + i] = run; run += loc[i]; }
    }
    if (t == 255) offs[NN] = part[255];
}

__global__ void k_scatter(const int* __restrict__ rcv, const int* __restrict__ offs,
                          int* __restrict__ cnt2, int* __restrict__ eidx){
    int e = blockIdx.x * 256 + threadIdx.x;
    if (e < NE){
        int r = rcv[e];
        int p = atomicAdd(&cnt2[r], 1);
        eidx[offs[r] + p] = e;
    }
}

// ---------------------------------------------------------------------------
// K1a: LayerNorm -> x_bf (bf16); vec = vf*vln_w -> vec_bf (bf16).
// ---------------------------------------------------------------------------
__global__ __launch_bounds__(128) void node_ln(
    const float* __restrict__ nf, const float* __restrict__ vf,
    const float* __restrict__ ln_s, const float* __restrict__ ln_b,
    const float* __restrict__ vlnw,
    ushort_t* __restrict__ x_bf, ushort_t* __restrict__ vec_bf)
{
    const int n = blockIdx.x, h = threadIdx.x;
    __shared__ float red[4];
    float xv = nf[(size_t)n*H + h];
    float s1 = xv, s2 = xv*xv;
    #pragma unroll
    for (int o = 32; o >= 1; o >>= 1){
        s1 += __shfl_xor(s1, o, 64);
        s2 += __shfl_xor(s2, o, 64);
    }
    const int wid = h >> 6;
    if ((h & 63) == 0){ red[wid] = s1; red[2+wid] = s2; }
    __syncthreads();
    float mean = (red[0] + red[1]) * (1.0f/H);
    float var  = (red[2] + red[3]) * (1.0f/H) - mean*mean;
    float x = (xv - mean) * rsqrtf(var + 1e-5f) * ln_s[h] + ln_b[h];
    x_bf[(size_t)n*H + h] = f2bf(x);
    float w = vlnw[h];
    #pragma unroll
    for (int l = 0; l < LD; l++){
        size_t i = ((size_t)n*LD + l)*H + h;
        vec_bf[i] = f2bf(vf[i] * w);
    }
}

// ---------------------------------------------------------------------------
// K1b (MFMA): [q|k|v] = x_bf @ wqkvT^T + bias, f32 out. M=10000 (guarded),
// N=384. 64 rows/block, 4 waves x 16-row stripe.
// ---------------------------------------------------------------------------
__global__ __launch_bounds__(256) void node_qkv(
    const ushort_t* __restrict__ x_bf, const ushort_t* __restrict__ wqkvT,
    const float* __restrict__ bq, const float* __restrict__ bk, const float* __restrict__ bv,
    float* __restrict__ q, float* __restrict__ k, float* __restrict__ v)
{
    const int tid  = threadIdx.x;
    const int lane = tid & 63;
    const int m0   = (tid >> 6) * 16;
    const int e0   = blockIdx.x * 64;

    const int mrow = lane & 15;
    const int kblk = lane >> 4;

    f32x4 acc[24];
    #pragma unroll
    for (int nt = 0; nt < 24; nt++) acc[nt] = (f32x4)(0.f);

    int arow = e0 + m0 + mrow; if (arow >= NN) arow = NN-1;
    const ushort_t* Arow = x_bf + (size_t)arow*H + kblk*8;
    const ushort_t* wb   = wqkvT + (size_t)mrow*H + kblk*8;

    #pragma unroll
    for (int ks = 0; ks < 4; ks++){
        bf16x8 a = *(const bf16x8*)(Arow + ks*32);
        #pragma unroll
        for (int nt = 0; nt < 24; nt++){
            bf16x8 b8 = *(const bf16x8*)(wb + (size_t)nt*16*H + ks*32);
            acc[nt] = __builtin_amdgcn_mfma_f32_16x16x32_bf16(a, b8, acc[nt], 0, 0, 0);
        }
    }
    float* outs[3] = {q, k, v};
    const float* bias[3] = {bq, bk, bv};
    #pragma unroll
    for (int g = 0; g < 3; g++){
        #pragma unroll
        for (int t = 0; t < 8; t++){
            int col = t*16 + mrow;
            float bb = bias[g][col];
            #pragma unroll
            for (int r = 0; r < 4; r++){
                int row = e0 + m0 + kblk*4 + r;
                if (row < NN) outs[g][(size_t)row*H + col] = acc[g*8+t][r] + bb;
            }
        }
    }
}

// ---------------------------------------------------------------------------
// K1c (MFMA): V5 = vec_bf @ wvecT^T, N=640 (tiles: 0-7 vec1, 8-15 vec2,
// 16-23 vec3, 24-31 Vt, 32-39 Vs). M=80000 rows, 64/block (8 nodes, aligned).
// Fused: vdot = sum_l vec1*vec2 (in-register + shfl); vec3/Vt/Vs staged
// through LDS, written bf16 coalesced.
// ---------------------------------------------------------------------------
__global__ __launch_bounds__(256) void node_vec(
    const ushort_t* __restrict__ vec_bf, const ushort_t* __restrict__ wvecT,
    float* __restrict__ vdot, ushort_t* __restrict__ vec3,
    ushort_t* __restrict__ Vt, ushort_t* __restrict__ Vs)
{
    __shared__ ushort_t st_s[64][136];

    const int tid  = threadIdx.x;
    const int lane = tid & 63;
    const int wv   = tid >> 6;
    const int m0   = wv * 16;
    const size_t r0 = (size_t)blockIdx.x * 64;       // global row = node*8+l

    const int mrow = lane & 15;
    const int kblk = lane >> 4;

    f32x4 acc[40];
    #pragma unroll
    for (int nt = 0; nt < 40; nt++) acc[nt] = (f32x4)(0.f);

    const ushort_t* Arow = vec_bf + (r0 + m0 + mrow)*H + kblk*8;
    const ushort_t* wb   = wvecT + (size_t)mrow*H + kblk*8;

    #pragma unroll
    for (int ks = 0; ks < 4; ks++){
        bf16x8 a = *(const bf16x8*)(Arow + ks*32);
        #pragma unroll
        for (int nt = 0; nt < 40; nt++){
            bf16x8 b8 = *(const bf16x8*)(wb + (size_t)nt*16*H + ks*32);
            acc[nt] = __builtin_amdgcn_mfma_f32_16x16x32_bf16(a, b8, acc[nt], 0, 0, 0);
        }
    }

    // vdot: pair tile t (vec1 cols) with t+8 (vec2 cols); reduce over l.
    #pragma unroll
    for (int t = 0; t < 8; t++){
        float p = acc[t][0]*acc[t+8][0] + acc[t][1]*acc[t+8][1]
                + acc[t][2]*acc[t+8][2] + acc[t][3]*acc[t+8][3];
        p += __shfl_xor(p, 16, 64);                  // kblk 0<->1, 2<->3
        if ((kblk & 1) == 0){
            int node = (int)(r0 >> 3) + wv*2 + (kblk >> 1);
            vdot[(size_t)node*H + t*16 + mrow] = p;
        }
    }

    // staged bf16 outputs: vec3 (tiles 16-23), Vt (24-31), Vs (32-39)
    ushort_t* outs[3] = {vec3, Vt, Vs};
    #pragma unroll
    for (int g = 0; g < 3; g++){
        __syncthreads();
        #pragma unroll
        for (int t = 0; t < 8; t++){
            int coln = t*16 + mrow;
            int lr = m0 + kblk*4;
            st_s[lr+0][coln] = f2bf(acc[16+g*8+t][0]);
            st_s[lr+1][coln] = f2bf(acc[16+g*8+t][1]);
            st_s[lr+2][coln] = f2bf(acc[16+g*8+t][2]);
            st_s[lr+3][coln] = f2bf(acc[16+g*8+t][3]);
        }
        __syncthreads();
        const int rr = tid >> 2, qq = tid & 3;       // 4 threads/row, 64B each
        uint4* dst = (uint4*)&outs[g][(r0 + rr)*H + qq*32];
        const uint4* src = (const uint4*)&st_s[rr][qq*32];
        dst[0] = src[0]; dst[1] = src[1]; dst[2] = src[2]; dst[3] = src[3];
    }
}

// ---------------------------------------------------------------------------
// K2 (MFMA): dk/dv = silu(ef@Wdk/dv + b), attention epilogue -> vj (bf16).
// ---------------------------------------------------------------------------
__global__ __launch_bounds__(256) void edge_attn(
    const ushort_t* __restrict__ ef_bf,
    const ushort_t* __restrict__ wdkT, const float* __restrict__ bdk,
    const ushort_t* __restrict__ wdvT, const float* __restrict__ bdv,
    const int* __restrict__ snd, const int* __restrict__ rcv,
    const float* __restrict__ dist,
    const float* __restrict__ q, const float* __restrict__ k, const float* __restrict__ v,
    ushort_t* __restrict__ vj)
{
    __shared__ ushort_t dk_s[64][136];
    __shared__ ushort_t dv_s[64][136];

    const int tid  = threadIdx.x;
    const int lane = tid & 63;
    const int m0   = (tid >> 6) * 16;
    const size_t e0 = (size_t)blockIdx.x * 64;

    const int mrow = lane & 15;
    const int kblk = lane >> 4;

    f32x4 accK[8], accV[8];
    #pragma unroll
    for (int nt = 0; nt < 8; nt++){ accK[nt] = (f32x4)(0.f); accV[nt] = (f32x4)(0.f); }

    const ushort_t* Arow = ef_bf + (e0 + m0 + mrow)*H + kblk*8;
    const ushort_t* wkb  = wdkT + (size_t)mrow*H + kblk*8;
    const ushort_t* wvb  = wdvT + (size_t)mrow*H + kblk*8;

    #pragma unroll
    for (int ks = 0; ks < 4; ks++){
        bf16x8 a = *(const bf16x8*)(Arow + ks*32);
        #pragma unroll
        for (int nt = 0; nt < 8; nt++){
            bf16x8 bk8 = *(const bf16x8*)(wkb + (size_t)nt*16*H + ks*32);
            accK[nt] = __builtin_amdgcn_mfma_f32_16x16x32_bf16(a, bk8, accK[nt], 0, 0, 0);
            bf16x8 bv8 = *(const bf16x8*)(wvb + (size_t)nt*16*H + ks*32);
            accV[nt] = __builtin_amdgcn_mfma_f32_16x16x32_bf16(a, bv8, accV[nt], 0, 0, 0);
        }
    }

    const int lrow = m0 + 4*kblk;
    #pragma unroll
    for (int nt = 0; nt < 8; nt++){
        int coln = nt*16 + mrow;
        float bkn = bdk[coln], bvn = bdv[coln];
        #pragma unroll
        for (int r = 0; r < 4; r++){
            dk_s[lrow + r][coln] = f2bf(silu_f(accK[nt][r] + bkn));
            dv_s[lrow + r][coln] = f2bf(silu_f(accV[nt][r] + bvn));
        }
    }
    __syncthreads();

    const int r  = tid >> 2, cq = tid & 3;
    const size_t e = e0 + r;
    const int s  = snd[e], rr = rcv[e];
    const float d = dist[e];
    const float cut = (d < 5.0f) ? 0.5f*(cosf(d*0.6283185307179586f) + 1.0f) : 0.0f;
    const float* qrow = q + (size_t)rr*H + cq*32;
    const float* krow = k + (size_t)s*H + cq*32;
    const float* vrow = v + (size_t)s*H + cq*32;
    ushort_t* vjrow = vj + e*H + cq*32;

    #pragma unroll
    for (int hh = 0; hh < 2; hh++){
        const int c0 = hh*16;
        float p = 0.f;
        #pragma unroll
        for (int j = 0; j < 4; j++){
            float4 q4 = *(const float4*)(qrow + c0 + 4*j);
            float4 k4 = *(const float4*)(krow + c0 + 4*j);
            uint2 du = *(const uint2*)&dk_s[r][cq*32 + c0 + 4*j];
            p += q4.x*k4.x*bf2f_lo(du.x) + q4.y*k4.y*bf2f_hi(du.x)
               + q4.z*k4.z*bf2f_lo(du.y) + q4.w*k4.w*bf2f_hi(du.y);
        }
        float attn = silu_f(p) * cut;
        #pragma unroll
        for (int j = 0; j < 4; j++){
            float4 v4 = *(const float4*)(vrow + c0 + 4*j);
            uint2 du = *(const uint2*)&dv_s[r][cq*32 + c0 + 4*j];
            uint2 u;
            u.x = pack2bf(v4.x*bf2f_lo(du.x)*attn, v4.y*bf2f_hi(du.x)*attn);
            u.y = pack2bf(v4.z*bf2f_lo(du.y)*attn, v4.w*bf2f_hi(du.y)*attn);
            *(uint2*)(vjrow + c0 + 4*j) = u;
        }
    }
}

// ---------------------------------------------------------------------------
// K3 (MFMA): s12 = silu(vj@Ws + bs) [E,256] bf16.
// ---------------------------------------------------------------------------
__global__ __launch_bounds__(256) void edge_s(
    const ushort_t* __restrict__ vj, const ushort_t* __restrict__ wsT,
    const float* __restrict__ bs, ushort_t* __restrict__ s12)
{
    __shared__ ushort_t s_s[64][264];

    const int tid  = threadIdx.x;
    const int lane = tid & 63;
    const int m0   = (tid >> 6) * 16;
    const size_t e0 = (size_t)blockIdx.x * 64;

    const int mrow = lane & 15;
    const int kblk = lane >> 4;

    f32x4 acc[16];
    #pragma unroll
    for (int nt = 0; nt < 16; nt++) acc[nt] = (f32x4)(0.f);

    const ushort_t* Arow = vj + (e0 + m0 + mrow)*H + kblk*8;
    const ushort_t* wb   = wsT + (size_t)mrow*H + kblk*8;

    #pragma unroll
    for (int ks = 0; ks < 4; ks++){
        bf16x8 a = *(const bf16x8*)(Arow + ks*32);
        #pragma unroll
        for (int nt = 0; nt < 16; nt++){
            bf16x8 b8 = *(const bf16x8*)(wb + (size_t)nt*16*H + ks*32);
            acc[nt] = __builtin_amdgcn_mfma_f32_16x16x32_bf16(a, b8, acc[nt], 0, 0, 0);
        }
    }

    const int lrow = m0 + 4*kblk;
    #pragma unroll
    for (int nt = 0; nt < 16; nt++){
        int coln = nt*16 + mrow;
        float bb = bs[coln];
        #pragma unroll
        for (int r = 0; r < 4; r++)
            s_s[lrow + r][coln] = f2bf(silu_f(acc[nt][r] + bb));
    }
    __syncthreads();

    const int r = tid >> 2, cq = tid & 3;
    const uint4* srcp = (const uint4*)&s_s[r][cq*64];
    uint4* dstp = (uint4*)&s12[(e0 + r)*256 + cq*64];
    #pragma unroll
    for (int j = 0; j < 8; j++) dstp[j] = srcp[j];
}

// ---------------------------------------------------------------------------
// K4 (f32 GEMV — precision-critical): df = silu(ef@Wf+bf) * w_dot.
// ---------------------------------------------------------------------------
__global__ __launch_bounds__(256) void edge_df(
    const float* __restrict__ ef, const float* __restrict__ Wf, const float* __restrict__ bf_,
    const int* __restrict__ eidx,
    const int* __restrict__ snd, const int* __restrict__ rcv,
    const float* __restrict__ dij,
    const ushort_t* __restrict__ Vt, const ushort_t* __restrict__ Vs,
    float* __restrict__ df)
{
    __shared__ float wf_s[H][64];
    __shared__ float e_s[16][H];
    __shared__ int   eidx_s[16];
    __shared__ int   snd_s[16];
    __shared__ int   rcv_s[16];
    __shared__ float dij_s[16][LD];

    const int tid = threadIdx.x;
    const int by = blockIdx.y;
    const int p0 = blockIdx.x * 16;

    if (tid < 16) eidx_s[tid] = eidx[p0 + tid];
    __syncthreads();

    for (int i = tid; i < H*16; i += 256){
        int row = i >> 4, c4 = i & 15;
        *(float4*)&wf_s[row][c4*4] = *(const float4*)&Wf[row*H + by*64 + c4*4];
    }
    for (int i = tid; i < 16*32; i += 256){
        int row = i >> 5, c4 = i & 31;
        *(float4*)&e_s[row][c4*4] = *(const float4*)&ef[(size_t)eidx_s[row]*H + c4*4];
    }
    if (tid < 16){ snd_s[tid] = snd[eidx_s[tid]]; rcv_s[tid] = rcv[eidx_s[tid]]; }
    if (tid < 16*LD){
        int row = tid >> 3, l = tid & 7;
        dij_s[row][l] = dij[(size_t)eidx_s[row]*LD + l];
    }
    __syncthreads();

    const int g = tid & 15, r0 = tid >> 4;
    float4 af = f4z();
    for (int kk = 0; kk < H; kk++){
        float4 w4 = *(float4*)&wf_s[kk][g*4];
        fma4(af, e_s[r0][kk], w4);
    }
    float4 bf4 = *(const float4*)&bf_[by*64 + g*4];
    float4 f4 = silu4(af, bf4);

    const int e = eidx_s[r0];
    const int s = snd_s[r0], rr = rcv_s[r0];
    const ushort_t* Ar = Vt + ((size_t)rr*LD)*H + by*64 + g*4;
    const ushort_t* Br = Vs + ((size_t)s*LD)*H + by*64 + g*4;

    float4 AB = f4z(), aa = f4z(), bb = f4z();
    float dd = 0.f;
    #pragma unroll
    for (int l = 0; l < LD; l++){
        float dl = dij_s[r0][l];
        dd = fmaf(dl, dl, dd);
        uint2 ua = *(const uint2*)&Ar[(size_t)l*H];
        uint2 ub = *(const uint2*)&Br[(size_t)l*H];
        float Ax = bf2f_lo(ua.x), Ay = bf2f_hi(ua.x), Az = bf2f_lo(ua.y), Aw = bf2f_hi(ua.y);
        float Bx = bf2f_lo(ub.x), By = bf2f_hi(ub.x), Bz = bf2f_lo(ub.y), Bw = bf2f_hi(ub.y);
        AB.x = fmaf(Ax, Bx, AB.x); AB.y = fmaf(Ay, By, AB.y);
        AB.z = fmaf(Az, Bz, AB.z); AB.w = fmaf(Aw, Bw, AB.w);
        aa.x = fmaf(Ax, dl, aa.x); aa.y = fmaf(Ay, dl, aa.y);
        aa.z = fmaf(Az, dl, aa.z); aa.w = fmaf(Aw, dl, aa.w);
        bb.x = fmaf(Bx, dl, bb.x); bb.y = fmaf(By, dl, bb.y);
        bb.z = fmaf(Bz, dl, bb.z); bb.w = fmaf(Bw, dl, bb.w);
    }
    float c = 2.0f - dd;
    float4 o = make_float4(f4.x*(AB.x - aa.x*bb.x*c),
                           f4.y*(AB.y - aa.y*bb.y*c),
                           f4.z*(AB.z - aa.z*bb.z*c),
                           f4.w*(AB.w - aa.w*bb.w*c));
    *(float4*)&df[(size_t)e*H + by*64 + g*4] = o;
}

// ---------------------------------------------------------------------------
// K5: per-receiver gather + fused node_post.
// ---------------------------------------------------------------------------
__global__ __launch_bounds__(128) void node_gather(
    const int* __restrict__ offs, const int* __restrict__ eidx, const int* __restrict__ snd,
    const ushort_t* __restrict__ vj, const ushort_t* __restrict__ s12,
    const float* __restrict__ dij, const ushort_t* __restrict__ vec,
    const float* __restrict__ Wo, const float* __restrict__ bo,
    const float* __restrict__ vdot, const ushort_t* __restrict__ vec3,
    float* __restrict__ dx, float* __restrict__ dvec)
{
    const int n = blockIdx.x, h = threadIdx.x;
    const int beg = offs[n], end = offs[n+1];
    float na = 0.f;
    float av[LD];
    #pragma unroll
    for (int l = 0; l < LD; l++) av[l] = 0.f;

    for (int i = beg; i < end; i++){
        int e = eidx[i];
        int s = snd[e];
        float vjv = bf2f_lo((unsigned int)vj[(size_t)e*H + h]);
        float s1 = bf2f_lo((unsigned int)s12[(size_t)e*256 + h]);
        float s2 = bf2f_lo((unsigned int)s12[(size_t)e*256 + 128 + h]);
        na += vjv;
        float4 d0 = *(const float4*)&dij[(size_t)e*LD];
        float4 d1 = *(const float4*)&dij[(size_t)e*LD + 4];
        const ushort_t* vr = &vec[(size_t)s*LD*H + h];
        av[0] = fmaf(bf2f_lo((unsigned int)vr[0*H]), s1, fmaf(d0.x, s2, av[0]));
        av[1] = fmaf(bf2f_lo((unsigned int)vr[1*H]), s1, fmaf(d0.y, s2, av[1]));
        av[2] = fmaf(bf2f_lo((unsigned int)vr[2*H]), s1, fmaf(d0.z, s2, av[2]));
        av[3] = fmaf(bf2f_lo((unsigned int)vr[3*H]), s1, fmaf(d0.w, s2, av[3]));
        av[4] = fmaf(bf2f_lo((unsigned int)vr[4*H]), s1, fmaf(d1.x, s2, av[4]));
        av[5] = fmaf(bf2f_lo((unsigned int)vr[5*H]), s1, fmaf(d1.y, s2, av[5]));
        av[6] = fmaf(bf2f_lo((unsigned int)vr[6*H]), s1, fmaf(d1.z, s2, av[6]));
        av[7] = fmaf(bf2f_lo((unsigned int)vr[7*H]), s1, fmaf(d1.w, s2, av[7]));
    }

    __shared__ float na_s[H];
    na_s[h] = na;
    __syncthreads();
    float o1 = bo[h], o2 = bo[H + h], o3 = bo[2*H + h];
    for (int kk = 0; kk < H; kk++){
        float a = na_s[kk];
        o1 = fmaf(a, Wo[kk*(3*H) + h], o1);
        o2 = fmaf(a, Wo[kk*(3*H) + H + h], o2);
        o3 = fmaf(a, Wo[kk*(3*H) + 2*H + h], o3);
    }
    dx[(size_t)n*H + h] = fmaf(vdot[(size_t)n*H + h], o2, o3);
    #pragma unroll
    for (int l = 0; l < LD; l++){
        size_t i2 = ((size_t)n*LD + l)*H + h;
        dvec[i2] = fmaf(bf2f_lo((unsigned int)vec3[i2]), o1, av[l]);
    }
}

// ---------------------------------------------------------------------------
extern "C" void kernel_launch(void* const* d_in, const int* in_sizes, int n_in,
                              void* d_out, int out_size, void* d_ws, size_t ws_size,
                              hipStream_t stream) {
    const float* nf    = (const float*)d_in[0];
    const float* ef    = (const float*)d_in[1];
    const float* vf    = (const float*)d_in[2];
    const float* dist  = (const float*)d_in[3];
    const float* dij   = (const float*)d_in[4];
    const int*   snd   = (const int*)d_in[5];
    const int*   rcv   = (const int*)d_in[6];
    const float* ln_s  = (const float*)d_in[7];
    const float* ln_b  = (const float*)d_in[8];
    const float* vlnw  = (const float*)d_in[9];
    const float* W_vec = (const float*)d_in[10];
    const float* Wq    = (const float*)d_in[11];
    const float* bq    = (const float*)d_in[12];
    const float* Wk    = (const float*)d_in[13];
    const float* bk    = (const float*)d_in[14];
    const float* Wv    = (const float*)d_in[15];
    const float* bv    = (const float*)d_in[16];
    const float* Wdk   = (const float*)d_in[17];
    const float* bdk   = (const float*)d_in[18];
    const float* Wdv   = (const float*)d_in[19];
    const float* bdv   = (const float*)d_in[20];
    const float* Ws    = (const float*)d_in[21];
    const float* bs    = (const float*)d_in[22];
    const float* Wo    = (const float*)d_in[23];
    const float* bo    = (const float*)d_in[24];
    const float* Wf    = (const float*)d_in[25];
    const float* bf_   = (const float*)d_in[26];
    const float* Wsrc  = (const float*)d_in[27];
    const float* Wtrg  = (const float*)d_in[28];

    float* out  = (float*)d_out;
    float* dx   = out;                                  // [NN, H]
    float* df   = out + (size_t)NN*H;                   // [NE, H]
    float* dvec = df + (size_t)NE*H;                    // [NN, LD, H]

    float* w = (float*)d_ws;
    size_t off = 0;
    float* q    = w + off; off += (size_t)NN*H;
    float* k    = w + off; off += (size_t)NN*H;
    float* v    = w + off; off += (size_t)NN*H;
    float* vdot = w + off; off += (size_t)NN*H;
    ushort_t* x_bf   = (ushort_t*)(w + off); off += (size_t)NN*H/2;
    ushort_t* vec_bf = (ushort_t*)(w + off); off += (size_t)NN*LD*H/2;
    ushort_t* vec3   = (ushort_t*)(w + off); off += (size_t)NN*LD*H/2;
    ushort_t* Vt     = (ushort_t*)(w + off); off += (size_t)NN*LD*H/2;
    ushort_t* Vs     = (ushort_t*)(w + off); off += (size_t)NN*LD*H/2;
    ushort_t* vj     = (ushort_t*)(w + off); off += (size_t)NE*H/2;
    // s12 [E,256] bf16 aliases ef_bf [E,128] bf16 (ef_bf dead after edge_attn;
    // edge_s writes s12 afterwards).
    ushort_t* s12    = (ushort_t*)(w + off); off += (size_t)NE*256/2;
    ushort_t* ef_bf  = s12;
    ushort_t* wqkvT = (ushort_t*)(w + off); off += 384*128/2;
    ushort_t* wvecT = (ushort_t*)(w + off); off += 640*128/2;
    ushort_t* wdkT  = (ushort_t*)(w + off); off += 128*128/2;
    ushort_t* wdvT  = (ushort_t*)(w + off); off += 128*128/2;
    ushort_t* wsT   = (ushort_t*)(w + off); off += 256*128/2;
    int* cnt  = (int*)(w + off); off += NN;
    int* cnt2 = (int*)(w + off); off += NN;
    int* offs = (int*)(w + off); off += NN + 1;
    int* eidx = (int*)(w + off); off += NE;

    hipMemsetAsync(cnt,  0, NN*sizeof(int), stream);
    hipMemsetAsync(cnt2, 0, NN*sizeof(int), stream);

    k_prepw<<<768, 256, 0, stream>>>(Wq, Wk, Wv, W_vec, Wtrg, Wsrc, Wdk, Wdv, Ws,
                                     wqkvT, wvecT, wdkT, wdvT, wsT);
    k_ef2bf<<<NE*H/8/256, 256, 0, stream>>>(ef, ef_bf);

    k_hist<<<(NE+255)/256, 256, 0, stream>>>(rcv, cnt);
    k_scan<<<1, 256, 0, stream>>>(cnt, offs);
    k_scatter<<<(NE+255)/256, 256, 0, stream>>>(rcv, offs, cnt2, eidx);

    node_ln<<<NN, 128, 0, stream>>>(nf, vf, ln_s, ln_b, vlnw, x_bf, vec_bf);

    node_qkv<<<(NN+63)/64, 256, 0, stream>>>(x_bf, wqkvT, bq, bk, bv, q, k, v);

    node_vec<<<NN*LD/64, 256, 0, stream>>>(vec_bf, wvecT, vdot, vec3, Vt, Vs);

    edge_attn<<<NE/64, 256, 0, stream>>>(ef_bf, wdkT, bdk, wdvT, bdv, snd, rcv, dist,
                                         q, k, v, vj);

    edge_df<<<dim3(NE/16, 2), 256, 0, stream>>>(ef, Wf, bf_, eidx, snd, rcv, dij, Vt, Vs, df);

    edge_s<<<NE/64, 256, 0, stream>>>(vj, wsT, bs, s12);

    node_gather<<<NN, 128, 0, stream>>>(offs, eidx, snd, vj, s12, dij, vec_bf,
                                        Wo, bo, vdot, vec3, dx, dvec);
}

// Round 8
// 831.671 us; speedup vs baseline: 3.8920x; 1.0080x over previous
//
#include <hip/hip_runtime.h>
#include <math.h>

#define NN 10000
#define NE 160000
#define H  128
#define LD 8

typedef unsigned short ushort_t;
typedef short bf16x8 __attribute__((ext_vector_type(8)));
typedef float f32x4 __attribute__((ext_vector_type(4)));

__device__ __forceinline__ float silu_f(float x){ return x / (1.0f + expf(-x)); }
__device__ __forceinline__ float4 f4z(){ return make_float4(0.f,0.f,0.f,0.f); }

__device__ __forceinline__ void fma4(float4& acc, float s, const float4 w){
    acc.x = fmaf(s, w.x, acc.x);
    acc.y = fmaf(s, w.y, acc.y);
    acc.z = fmaf(s, w.z, acc.z);
    acc.w = fmaf(s, w.w, acc.w);
}

__device__ __forceinline__ float4 silu4(float4 a, float4 b){
    return make_float4(silu_f(a.x+b.x), silu_f(a.y+b.y), silu_f(a.z+b.z), silu_f(a.w+b.w));
}

__device__ __forceinline__ ushort_t f2bf(float f){
    union { float f; unsigned int u; } x; x.f = f;
    unsigned int r = x.u + 0x7FFFu + ((x.u >> 16) & 1u);
    return (ushort_t)(r >> 16);
}
__device__ __forceinline__ unsigned int pack2bf(float a, float b){
    return (unsigned int)f2bf(a) | ((unsigned int)f2bf(b) << 16);
}
__device__ __forceinline__ float bf2f_hi(unsigned int u){
    union { unsigned int u; float f; } x; x.u = u & 0xffff0000u; return x.f;
}
__device__ __forceinline__ float bf2f_lo(unsigned int u){
    union { unsigned int u; float f; } x; x.u = u << 16; return x.f;
}

// ---------------------------------------------------------------------------
// Prep: transpose GEMM weights to bf16 W^T[n][k]; cast ef to bf16.
// ---------------------------------------------------------------------------
__global__ void k_prepw(const float* __restrict__ Wq, const float* __restrict__ Wk,
                        const float* __restrict__ Wv, const float* __restrict__ W_vec,
                        const float* __restrict__ Wtrg, const float* __restrict__ Wsrc,
                        const float* __restrict__ Wdk, const float* __restrict__ Wdv,
                        const float* __restrict__ Ws,
                        ushort_t* __restrict__ wqkvT, ushort_t* __restrict__ wvecT,
                        ushort_t* __restrict__ wdkT, ushort_t* __restrict__ wdvT,
                        ushort_t* __restrict__ wsT){
    int i = blockIdx.x * 256 + threadIdx.x;          // 0 .. 196607
    int n = i >> 7, kk = i & 127;
    if (n < 384){                                    // wqkvT
        float v;
        if (n < 128)      v = Wq[kk*128 + n];
        else if (n < 256) v = Wk[kk*128 + (n-128)];
        else              v = Wv[kk*128 + (n-256)];
        wqkvT[n*128 + kk] = f2bf(v);
    } else if (n < 1024){                            // wvecT (640 rows)
        int m = n - 384;
        float v;
        if (m < 384)      v = W_vec[kk*384 + m];
        else if (m < 512) v = Wtrg[kk*128 + (m-384)];
        else              v = Wsrc[kk*128 + (m-512)];
        wvecT[m*128 + kk] = f2bf(v);
    } else if (n < 1152){
        int m = n - 1024;
        wdkT[m*128 + kk] = f2bf(Wdk[kk*128 + m]);
    } else if (n < 1280){
        int m = n - 1152;
        wdvT[m*128 + kk] = f2bf(Wdv[kk*128 + m]);
    } else if (n < 1536){
        int m = n - 1280;
        wsT[m*128 + kk] = f2bf(Ws[kk*256 + m]);
    }
}

__global__ void k_ef2bf(const float* __restrict__ ef, ushort_t* __restrict__ ef_bf){
    size_t i = (size_t)blockIdx.x * 256 + threadIdx.x;   // over E*H/8
    const float4* s = (const float4*)ef;
    float4 a = s[2*i], b = s[2*i+1];
    uint4 u;
    u.x = pack2bf(a.x, a.y); u.y = pack2bf(a.z, a.w);
    u.z = pack2bf(b.x, b.y); u.w = pack2bf(b.z, b.w);
    ((uint4*)ef_bf)[i] = u;
}

// ---------------------------------------------------------------------------
// Sort edges by receiver: histogram -> exclusive scan -> rank scatter.
// ---------------------------------------------------------------------------
__global__ void k_hist(const int* __restrict__ rcv, int* __restrict__ cnt){
    int e = blockIdx.x * 256 + threadIdx.x;
    if (e < NE) atomicAdd(&cnt[rcv[e]], 1);
}

__global__ __launch_bounds__(256) void k_scan(const int* __restrict__ cnt, int* __restrict__ offs){
    __shared__ int part[256];
    const int t = threadIdx.x;
    const int CH = 40;
    int loc[CH];
    int base = t * CH;
    int lsum = 0;
    if (base < NN){
        #pragma unroll
        for (int i = 0; i < CH; i++){ loc[i] = cnt[base + i]; lsum += loc[i]; }
    }
    part[t] = lsum;
    __syncthreads();
    for (int off = 1; off < 256; off <<= 1){
        int v = (t >= off) ? part[t - off] : 0;
        __syncthreads();
        part[t] += v;
        __syncthreads();
    }
    int ex = part[t] - lsum;
    if (base < NN){
        int run = ex;
        #pragma unroll
        for (int i = 0; i < CH; i++){ offs[base + i] = run; run += loc[i]; }
    }
    if (t == 255) offs[NN] = part[255];
}

__global__ void k_scatter(const int* __restrict__ rcv, const int* __restrict__ offs,
                          int* __restrict__ cnt2, int* __restrict__ eidx){
    int e = blockIdx.x * 256 + threadIdx.x;
    if (e < NE){
        int r = rcv[e];
        int p = atomicAdd(&cnt2[r], 1);
        eidx[offs[r] + p] = e;
    }
}

// ---------------------------------------------------------------------------
// K1a: LayerNorm -> x_bf (bf16); vec = vf*vln_w -> vec_bf (bf16).
// ---------------------------------------------------------------------------
__global__ __launch_bounds__(128) void node_ln(
    const float* __restrict__ nf, const float* __restrict__ vf,
    const float* __restrict__ ln_s, const float* __restrict__ ln_b,
    const float* __restrict__ vlnw,
    ushort_t* __restrict__ x_bf, ushort_t* __restrict__ vec_bf)
{
    const int n = blockIdx.x, h = threadIdx.x;
    __shared__ float red[4];
    float xv = nf[(size_t)n*H + h];
    float s1 = xv, s2 = xv*xv;
    #pragma unroll
    for (int o = 32; o >= 1; o >>= 1){
        s1 += __shfl_xor(s1, o, 64);
        s2 += __shfl_xor(s2, o, 64);
    }
    const int wid = h >> 6;
    if ((h & 63) == 0){ red[wid] = s1; red[2+wid] = s2; }
    __syncthreads();
    float mean = (red[0] + red[1]) * (1.0f/H);
    float var  = (red[2] + red[3]) * (1.0f/H) - mean*mean;
    float x = (xv - mean) * rsqrtf(var + 1e-5f) * ln_s[h] + ln_b[h];
    x_bf[(size_t)n*H + h] = f2bf(x);
    float w = vlnw[h];
    #pragma unroll
    for (int l = 0; l < LD; l++){
        size_t i = ((size_t)n*LD + l)*H + h;
        vec_bf[i] = f2bf(vf[i] * w);
    }
}

// ---------------------------------------------------------------------------
// K1b (MFMA): [q|k|v] = x_bf @ wqkvT^T + bias, f32 out.
// ---------------------------------------------------------------------------
__global__ __launch_bounds__(256) void node_qkv(
    const ushort_t* __restrict__ x_bf, const ushort_t* __restrict__ wqkvT,
    const float* __restrict__ bq, const float* __restrict__ bk, const float* __restrict__ bv,
    float* __restrict__ q, float* __restrict__ k, float* __restrict__ v)
{
    const int tid  = threadIdx.x;
    const int lane = tid & 63;
    const int m0   = (tid >> 6) * 16;
    const int e0   = blockIdx.x * 64;

    const int mrow = lane & 15;
    const int kblk = lane >> 4;

    f32x4 acc[24];
    #pragma unroll
    for (int nt = 0; nt < 24; nt++) acc[nt] = (f32x4)(0.f);

    int arow = e0 + m0 + mrow; if (arow >= NN) arow = NN-1;
    const ushort_t* Arow = x_bf + (size_t)arow*H + kblk*8;
    const ushort_t* wb   = wqkvT + (size_t)mrow*H + kblk*8;

    #pragma unroll
    for (int ks = 0; ks < 4; ks++){
        bf16x8 a = *(const bf16x8*)(Arow + ks*32);
        #pragma unroll
        for (int nt = 0; nt < 24; nt++){
            bf16x8 b8 = *(const bf16x8*)(wb + (size_t)nt*16*H + ks*32);
            acc[nt] = __builtin_amdgcn_mfma_f32_16x16x32_bf16(a, b8, acc[nt], 0, 0, 0);
        }
    }
    float* outs[3] = {q, k, v};
    const float* bias[3] = {bq, bk, bv};
    #pragma unroll
    for (int g = 0; g < 3; g++){
        #pragma unroll
        for (int t = 0; t < 8; t++){
            int col = t*16 + mrow;
            float bb = bias[g][col];
            #pragma unroll
            for (int r = 0; r < 4; r++){
                int row = e0 + m0 + kblk*4 + r;
                if (row < NN) outs[g][(size_t)row*H + col] = acc[g*8+t][r] + bb;
            }
        }
    }
}

// ---------------------------------------------------------------------------
// K1c (MFMA): V5 = vec_bf @ wvecT^T, N=640; fused vdot + bf16 outputs.
// ---------------------------------------------------------------------------
__global__ __launch_bounds__(256) void node_vec(
    const ushort_t* __restrict__ vec_bf, const ushort_t* __restrict__ wvecT,
    float* __restrict__ vdot, ushort_t* __restrict__ vec3,
    ushort_t* __restrict__ Vt, ushort_t* __restrict__ Vs)
{
    __shared__ ushort_t st_s[64][136];

    const int tid  = threadIdx.x;
    const int lane = tid & 63;
    const int wv   = tid >> 6;
    const int m0   = wv * 16;
    const size_t r0 = (size_t)blockIdx.x * 64;       // global row = node*8+l

    const int mrow = lane & 15;
    const int kblk = lane >> 4;

    f32x4 acc[40];
    #pragma unroll
    for (int nt = 0; nt < 40; nt++) acc[nt] = (f32x4)(0.f);

    const ushort_t* Arow = vec_bf + (r0 + m0 + mrow)*H + kblk*8;
    const ushort_t* wb   = wvecT + (size_t)mrow*H + kblk*8;

    #pragma unroll
    for (int ks = 0; ks < 4; ks++){
        bf16x8 a = *(const bf16x8*)(Arow + ks*32);
        #pragma unroll
        for (int nt = 0; nt < 40; nt++){
            bf16x8 b8 = *(const bf16x8*)(wb + (size_t)nt*16*H + ks*32);
            acc[nt] = __builtin_amdgcn_mfma_f32_16x16x32_bf16(a, b8, acc[nt], 0, 0, 0);
        }
    }

    #pragma unroll
    for (int t = 0; t < 8; t++){
        float p = acc[t][0]*acc[t+8][0] + acc[t][1]*acc[t+8][1]
                + acc[t][2]*acc[t+8][2] + acc[t][3]*acc[t+8][3];
        p += __shfl_xor(p, 16, 64);                  // kblk 0<->1, 2<->3
        if ((kblk & 1) == 0){
            int node = (int)(r0 >> 3) + wv*2 + (kblk >> 1);
            vdot[(size_t)node*H + t*16 + mrow] = p;
        }
    }

    ushort_t* outs[3] = {vec3, Vt, Vs};
    #pragma unroll
    for (int g = 0; g < 3; g++){
        __syncthreads();
        #pragma unroll
        for (int t = 0; t < 8; t++){
            int coln = t*16 + mrow;
            int lr = m0 + kblk*4;
            st_s[lr+0][coln] = f2bf(acc[16+g*8+t][0]);
            st_s[lr+1][coln] = f2bf(acc[16+g*8+t][1]);
            st_s[lr+2][coln] = f2bf(acc[16+g*8+t][2]);
            st_s[lr+3][coln] = f2bf(acc[16+g*8+t][3]);
        }
        __syncthreads();
        const int rr = tid >> 2, qq = tid & 3;
        uint4* dst = (uint4*)&outs[g][(r0 + rr)*H + qq*32];
        const uint4* src = (const uint4*)&st_s[rr][qq*32];
        dst[0] = src[0]; dst[1] = src[1]; dst[2] = src[2]; dst[3] = src[3];
    }
}

// ---------------------------------------------------------------------------
// K2 (MFMA): dk/dv = silu(ef@Wdk/dv + b), attention epilogue -> vj (bf16).
// ---------------------------------------------------------------------------
__global__ __launch_bounds__(256) void edge_attn(
    const ushort_t* __restrict__ ef_bf,
    const ushort_t* __restrict__ wdkT, const float* __restrict__ bdk,
    const ushort_t* __restrict__ wdvT, const float* __restrict__ bdv,
    const int* __restrict__ snd, const int* __restrict__ rcv,
    const float* __restrict__ dist,
    const float* __restrict__ q, const float* __restrict__ k, const float* __restrict__ v,
    ushort_t* __restrict__ vj)
{
    __shared__ ushort_t dk_s[64][136];
    __shared__ ushort_t dv_s[64][136];

    const int tid  = threadIdx.x;
    const int lane = tid & 63;
    const int m0   = (tid >> 6) * 16;
    const size_t e0 = (size_t)blockIdx.x * 64;

    const int mrow = lane & 15;
    const int kblk = lane >> 4;

    f32x4 accK[8], accV[8];
    #pragma unroll
    for (int nt = 0; nt < 8; nt++){ accK[nt] = (f32x4)(0.f); accV[nt] = (f32x4)(0.f); }

    const ushort_t* Arow = ef_bf + (e0 + m0 + mrow)*H + kblk*8;
    const ushort_t* wkb  = wdkT + (size_t)mrow*H + kblk*8;
    const ushort_t* wvb  = wdvT + (size_t)mrow*H + kblk*8;

    #pragma unroll
    for (int ks = 0; ks < 4; ks++){
        bf16x8 a = *(const bf16x8*)(Arow + ks*32);
        #pragma unroll
        for (int nt = 0; nt < 8; nt++){
            bf16x8 bk8 = *(const bf16x8*)(wkb + (size_t)nt*16*H + ks*32);
            accK[nt] = __builtin_amdgcn_mfma_f32_16x16x32_bf16(a, bk8, accK[nt], 0, 0, 0);
            bf16x8 bv8 = *(const bf16x8*)(wvb + (size_t)nt*16*H + ks*32);
            accV[nt] = __builtin_amdgcn_mfma_f32_16x16x32_bf16(a, bv8, accV[nt], 0, 0, 0);
        }
    }

    const int lrow = m0 + 4*kblk;
    #pragma unroll
    for (int nt = 0; nt < 8; nt++){
        int coln = nt*16 + mrow;
        float bkn = bdk[coln], bvn = bdv[coln];
        #pragma unroll
        for (int r = 0; r < 4; r++){
            dk_s[lrow + r][coln] = f2bf(silu_f(accK[nt][r] + bkn));
            dv_s[lrow + r][coln] = f2bf(silu_f(accV[nt][r] + bvn));
        }
    }
    __syncthreads();

    const int r  = tid >> 2, cq = tid & 3;
    const size_t e = e0 + r;
    const int s  = snd[e], rr = rcv[e];
    const float d = dist[e];
    const float cut = (d < 5.0f) ? 0.5f*(cosf(d*0.6283185307179586f) + 1.0f) : 0.0f;
    const float* qrow = q + (size_t)rr*H + cq*32;
    const float* krow = k + (size_t)s*H + cq*32;
    const float* vrow = v + (size_t)s*H + cq*32;
    ushort_t* vjrow = vj + e*H + cq*32;

    #pragma unroll
    for (int hh = 0; hh < 2; hh++){
        const int c0 = hh*16;
        float p = 0.f;
        #pragma unroll
        for (int j = 0; j < 4; j++){
            float4 q4 = *(const float4*)(qrow + c0 + 4*j);
            float4 k4 = *(const float4*)(krow + c0 + 4*j);
            uint2 du = *(const uint2*)&dk_s[r][cq*32 + c0 + 4*j];
            p += q4.x*k4.x*bf2f_lo(du.x) + q4.y*k4.y*bf2f_hi(du.x)
               + q4.z*k4.z*bf2f_lo(du.y) + q4.w*k4.w*bf2f_hi(du.y);
        }
        float attn = silu_f(p) * cut;
        #pragma unroll
        for (int j = 0; j < 4; j++){
            float4 v4 = *(const float4*)(vrow + c0 + 4*j);
            uint2 du = *(const uint2*)&dv_s[r][cq*32 + c0 + 4*j];
            uint2 u;
            u.x = pack2bf(v4.x*bf2f_lo(du.x)*attn, v4.y*bf2f_hi(du.x)*attn);
            u.y = pack2bf(v4.z*bf2f_lo(du.y)*attn, v4.w*bf2f_hi(du.y)*attn);
            *(uint2*)(vjrow + c0 + 4*j) = u;
        }
    }
}

// ---------------------------------------------------------------------------
// K3 (MFMA): s12 = silu(vj@Ws + bs) [E,256] bf16.
// ---------------------------------------------------------------------------
__global__ __launch_bounds__(256) void edge_s(
    const ushort_t* __restrict__ vj, const ushort_t* __restrict__ wsT,
    const float* __restrict__ bs, ushort_t* __restrict__ s12)
{
    __shared__ ushort_t s_s[64][264];

    const int tid  = threadIdx.x;
    const int lane = tid & 63;
    const int m0   = (tid >> 6) * 16;
    const size_t e0 = (size_t)blockIdx.x * 64;

    const int mrow = lane & 15;
    const int kblk = lane >> 4;

    f32x4 acc[16];
    #pragma unroll
    for (int nt = 0; nt < 16; nt++) acc[nt] = (f32x4)(0.f);

    const ushort_t* Arow = vj + (e0 + m0 + mrow)*H + kblk*8;
    const ushort_t* wb   = wsT + (size_t)mrow*H + kblk*8;

    #pragma unroll
    for (int ks = 0; ks < 4; ks++){
        bf16x8 a = *(const bf16x8*)(Arow + ks*32);
        #pragma unroll
        for (int nt = 0; nt < 16; nt++){
            bf16x8 b8 = *(const bf16x8*)(wb + (size_t)nt*16*H + ks*32);
            acc[nt] = __builtin_amdgcn_mfma_f32_16x16x32_bf16(a, b8, acc[nt], 0, 0, 0);
        }
    }

    const int lrow = m0 + 4*kblk;
    #pragma unroll
    for (int nt = 0; nt < 16; nt++){
        int coln = nt*16 + mrow;
        float bb = bs[coln];
        #pragma unroll
        for (int r = 0; r < 4; r++)
            s_s[lrow + r][coln] = f2bf(silu_f(acc[nt][r] + bb));
    }
    __syncthreads();

    const int r = tid >> 2, cq = tid & 3;
    const uint4* srcp = (const uint4*)&s_s[r][cq*64];
    uint4* dstp = (uint4*)&s12[(e0 + r)*256 + cq*64];
    #pragma unroll
    for (int j = 0; j < 8; j++) dstp[j] = srcp[j];
}

// ---------------------------------------------------------------------------
// K4 (f32 GEMV — proven-precision path): df = silu(ef@Wf+bf) * w_dot with
// w_dot = (A.B) - a*b*(2-|d|^2), A=Vt[rcv], B=Vs[snd] (bf16).
// 32 edges/block, column-quarter per blockIdx.y -> LDS 34KB, 4 blocks/CU.
// e_s padded to stride 132 (kills the 4-way same-bank conflict on e_s[r0][kk]).
// ---------------------------------------------------------------------------
__global__ __launch_bounds__(256) void edge_df(
    const float* __restrict__ ef, const float* __restrict__ Wf, const float* __restrict__ bf_,
    const int* __restrict__ eidx,
    const int* __restrict__ snd, const int* __restrict__ rcv,
    const float* __restrict__ dij,
    const ushort_t* __restrict__ Vt, const ushort_t* __restrict__ Vs,
    float* __restrict__ df)
{
    __shared__ float wf_s[H][32];
    __shared__ float e_s[32][H+4];
    __shared__ int   eidx_s[32];
    __shared__ int   snd_s[32];
    __shared__ int   rcv_s[32];
    __shared__ float dij_s[32][LD];

    const int tid = threadIdx.x;
    const int by  = blockIdx.y;          // column quarter [by*32, by*32+32)
    const int p0  = blockIdx.x * 32;     // sorted positions [p0, p0+32)

    if (tid < 32) eidx_s[tid] = eidx[p0 + tid];
    __syncthreads();
    if (tid < 32){ int e = eidx_s[tid]; snd_s[tid] = snd[e]; rcv_s[tid] = rcv[e]; }
    for (int i = tid; i < 32*LD; i += 256){
        int row = i >> 3, l = i & 7;
        dij_s[row][l] = dij[(size_t)eidx_s[row]*LD + l];
    }
    for (int i = tid; i < H*8; i += 256){            // Wf quarter: 128 x 8 f4
        int row = i >> 3, c4 = i & 7;
        *(float4*)&wf_s[row][c4*4] = *(const float4*)&Wf[row*H + by*32 + c4*4];
    }
    for (int i = tid; i < 32*32; i += 256){          // 32 rows x 32 f4
        int row = i >> 5, c4 = i & 31;
        *(float4*)&e_s[row][c4*4] = *(const float4*)&ef[(size_t)eidx_s[row]*H + c4*4];
    }
    __syncthreads();

    const int g = tid & 7, r0 = tid >> 3;            // 8 col-groups x 32 edges
    float4 af = f4z();
    for (int kk = 0; kk < H; kk++){
        float4 w4 = *(float4*)&wf_s[kk][g*4];
        fma4(af, e_s[r0][kk], w4);
    }
    float4 bf4 = *(const float4*)&bf_[by*32 + g*4];
    float4 f4v = silu4(af, bf4);

    const int e = eidx_s[r0];
    const int s = snd_s[r0], rr = rcv_s[r0];
    const ushort_t* Ar = Vt + (size_t)rr*LD*H + by*32 + g*4;
    const ushort_t* Br = Vs + (size_t)s*LD*H + by*32 + g*4;

    float4 AB = f4z(), aa = f4z(), bb = f4z();
    float dd = 0.f;
    #pragma unroll
    for (int l = 0; l < LD; l++){
        float dl = dij_s[r0][l];
        dd = fmaf(dl, dl, dd);
        uint2 ua = *(const uint2*)&Ar[(size_t)l*H];
        uint2 ub = *(const uint2*)&Br[(size_t)l*H];
        float Ax = bf2f_lo(ua.x), Ay = bf2f_hi(ua.x), Az = bf2f_lo(ua.y), Aw = bf2f_hi(ua.y);
        float Bx = bf2f_lo(ub.x), By = bf2f_hi(ub.x), Bz = bf2f_lo(ub.y), Bw = bf2f_hi(ub.y);
        AB.x = fmaf(Ax, Bx, AB.x); AB.y = fmaf(Ay, By, AB.y);
        AB.z = fmaf(Az, Bz, AB.z); AB.w = fmaf(Aw, Bw, AB.w);
        aa.x = fmaf(Ax, dl, aa.x); aa.y = fmaf(Ay, dl, aa.y);
        aa.z = fmaf(Az, dl, aa.z); aa.w = fmaf(Aw, dl, aa.w);
        bb.x = fmaf(Bx, dl, bb.x); bb.y = fmaf(By, dl, bb.y);
        bb.z = fmaf(Bz, dl, bb.z); bb.w = fmaf(Bw, dl, bb.w);
    }
    float c = 2.0f - dd;
    float4 o = make_float4(f4v.x*(AB.x - aa.x*bb.x*c),
                           f4v.y*(AB.y - aa.y*bb.y*c),
                           f4v.z*(AB.z - aa.z*bb.z*c),
                           f4v.w*(AB.w - aa.w*bb.w*c));
    *(float4*)&df[(size_t)e*H + by*32 + g*4] = o;
}

// ---------------------------------------------------------------------------
// K5: per-receiver gather + fused node_post. 256 threads: two interleaved
// edge streams per node, LDS combine.
// ---------------------------------------------------------------------------
__global__ __launch_bounds__(256) void node_gather(
    const int* __restrict__ offs, const int* __restrict__ eidx, const int* __restrict__ snd,
    const ushort_t* __restrict__ vj, const ushort_t* __restrict__ s12,
    const float* __restrict__ dij, const ushort_t* __restrict__ vec,
    const float* __restrict__ Wo, const float* __restrict__ bo,
    const float* __restrict__ vdot, const ushort_t* __restrict__ vec3,
    float* __restrict__ dx, float* __restrict__ dvec)
{
    const int n = blockIdx.x;
    const int tid = threadIdx.x;
    const int h = tid & 127;
    const int par = tid >> 7;
    const int beg = offs[n], end = offs[n+1];
    float na = 0.f;
    float av[LD];
    #pragma unroll
    for (int l = 0; l < LD; l++) av[l] = 0.f;

    for (int i = beg + par; i < end; i += 2){
        int e = eidx[i];
        int s = snd[e];
        float vjv = bf2f_lo((unsigned int)vj[(size_t)e*H + h]);
        float s1 = bf2f_lo((unsigned int)s12[(size_t)e*256 + h]);
        float s2 = bf2f_lo((unsigned int)s12[(size_t)e*256 + 128 + h]);
        na += vjv;
        float4 d0 = *(const float4*)&dij[(size_t)e*LD];
        float4 d1 = *(const float4*)&dij[(size_t)e*LD + 4];
        const ushort_t* vr = &vec[(size_t)s*LD*H + h];
        av[0] = fmaf(bf2f_lo((unsigned int)vr[0*H]), s1, fmaf(d0.x, s2, av[0]));
        av[1] = fmaf(bf2f_lo((unsigned int)vr[1*H]), s1, fmaf(d0.y, s2, av[1]));
        av[2] = fmaf(bf2f_lo((unsigned int)vr[2*H]), s1, fmaf(d0.z, s2, av[2]));
        av[3] = fmaf(bf2f_lo((unsigned int)vr[3*H]), s1, fmaf(d0.w, s2, av[3]));
        av[4] = fmaf(bf2f_lo((unsigned int)vr[4*H]), s1, fmaf(d1.x, s2, av[4]));
        av[5] = fmaf(bf2f_lo((unsigned int)vr[5*H]), s1, fmaf(d1.y, s2, av[5]));
        av[6] = fmaf(bf2f_lo((unsigned int)vr[6*H]), s1, fmaf(d1.z, s2, av[6]));
        av[7] = fmaf(bf2f_lo((unsigned int)vr[7*H]), s1, fmaf(d1.w, s2, av[7]));
    }

    __shared__ float red_s[LD+1][128];
    if (par == 0){
        #pragma unroll
        for (int l = 0; l < LD; l++) red_s[l][h] = av[l];
        red_s[LD][h] = na;
    }
    __syncthreads();
    if (par == 1){
        #pragma unroll
        for (int l = 0; l < LD; l++) red_s[l][h] += av[l];
        red_s[LD][h] += na;
    }
    __syncthreads();

    if (par == 0){
        float o1 = bo[h], o2 = bo[H + h], o3 = bo[2*H + h];
        for (int kk = 0; kk < H; kk++){
            float a = red_s[LD][kk];
            o1 = fmaf(a, Wo[kk*(3*H) + h], o1);
            o2 = fmaf(a, Wo[kk*(3*H) + H + h], o2);
            o3 = fmaf(a, Wo[kk*(3*H) + 2*H + h], o3);
        }
        dx[(size_t)n*H + h] = fmaf(vdot[(size_t)n*H + h], o2, o3);
        #pragma unroll
        for (int l = 0; l < LD; l++){
            size_t i2 = ((size_t)n*LD + l)*H + h;
            dvec[i2] = fmaf(bf2f_lo((unsigned int)vec3[i2]), o1, red_s[l][h]);
        }
    }
}

// ---------------------------------------------------------------------------
extern "C" void kernel_launch(void* const* d_in, const int* in_sizes, int n_in,
                              void* d_out, int out_size, void* d_ws, size_t ws_size,
                              hipStream_t stream) {
    const float* nf    = (const float*)d_in[0];
    const float* ef    = (const float*)d_in[1];
    const float* vf    = (const float*)d_in[2];
    const float* dist  = (const float*)d_in[3];
    const float* dij   = (const float*)d_in[4];
    const int*   snd   = (const int*)d_in[5];
    const int*   rcv   = (const int*)d_in[6];
    const float* ln_s  = (const float*)d_in[7];
    const float* ln_b  = (const float*)d_in[8];
    const float* vlnw  = (const float*)d_in[9];
    const float* W_vec = (const float*)d_in[10];
    const float* Wq    = (const float*)d_in[11];
    const float* bq    = (const float*)d_in[12];
    const float* Wk    = (const float*)d_in[13];
    const float* bk    = (const float*)d_in[14];
    const float* Wv    = (const float*)d_in[15];
    const float* bv    = (const float*)d_in[16];
    const float* Wdk   = (const float*)d_in[17];
    const float* bdk   = (const float*)d_in[18];
    const float* Wdv   = (const float*)d_in[19];
    const float* bdv   = (const float*)d_in[20];
    const float* Ws    = (const float*)d_in[21];
    const float* bs    = (const float*)d_in[22];
    const float* Wo    = (const float*)d_in[23];
    const float* bo    = (const float*)d_in[24];
    const float* Wf    = (const float*)d_in[25];
    const float* bf_   = (const float*)d_in[26];
    const float* Wsrc  = (const float*)d_in[27];
    const float* Wtrg  = (const float*)d_in[28];

    float* out  = (float*)d_out;
    float* dx   = out;                                  // [NN, H]
    float* df   = out + (size_t)NN*H;                   // [NE, H]
    float* dvec = df + (size_t)NE*H;                    // [NN, LD, H]

    float* w = (float*)d_ws;
    size_t off = 0;
    float* q    = w + off; off += (size_t)NN*H;
    float* k    = w + off; off += (size_t)NN*H;
    float* v    = w + off; off += (size_t)NN*H;
    float* vdot = w + off; off += (size_t)NN*H;
    ushort_t* x_bf   = (ushort_t*)(w + off); off += (size_t)NN*H/2;
    ushort_t* vec_bf = (ushort_t*)(w + off); off += (size_t)NN*LD*H/2;
    ushort_t* vec3   = (ushort_t*)(w + off); off += (size_t)NN*LD*H/2;
    ushort_t* Vt     = (ushort_t*)(w + off); off += (size_t)NN*LD*H/2;
    ushort_t* Vs     = (ushort_t*)(w + off); off += (size_t)NN*LD*H/2;
    ushort_t* vj     = (ushort_t*)(w + off); off += (size_t)NE*H/2;
    // s12 [E,256] bf16 aliases ef_bf [E,128] bf16 (ef_bf dead after edge_attn;
    // edge_s writes s12 afterwards).
    ushort_t* s12    = (ushort_t*)(w + off); off += (size_t)NE*256/2;
    ushort_t* ef_bf  = s12;
    ushort_t* wqkvT = (ushort_t*)(w + off); off += 384*128/2;
    ushort_t* wvecT = (ushort_t*)(w + off); off += 640*128/2;
    ushort_t* wdkT  = (ushort_t*)(w + off); off += 128*128/2;
    ushort_t* wdvT  = (ushort_t*)(w + off); off += 128*128/2;
    ushort_t* wsT   = (ushort_t*)(w + off); off += 256*128/2;
    int* cnt  = (int*)(w + off); off += NN;
    int* cnt2 = (int*)(w + off); off += NN;
    int* offs = (int*)(w + off); off += NN + 1;
    int* eidx = (int*)(w + off); off += NE;

    hipMemsetAsync(cnt,  0, NN*sizeof(int), stream);
    hipMemsetAsync(cnt2, 0, NN*sizeof(int), stream);

    k_prepw<<<768, 256, 0, stream>>>(Wq, Wk, Wv, W_vec, Wtrg, Wsrc, Wdk, Wdv, Ws,
                                     wqkvT, wvecT, wdkT, wdvT, wsT);
    k_ef2bf<<<NE*H/8/256, 256, 0, stream>>>(ef, ef_bf);

    k_hist<<<(NE+255)/256, 256, 0, stream>>>(rcv, cnt);
    k_scan<<<1, 256, 0, stream>>>(cnt, offs);
    k_scatter<<<(NE+255)/256, 256, 0, stream>>>(rcv, offs, cnt2, eidx);

    node_ln<<<NN, 128, 0, stream>>>(nf, vf, ln_s, ln_b, vlnw, x_bf, vec_bf);

    node_qkv<<<(NN+63)/64, 256, 0, stream>>>(x_bf, wqkvT, bq, bk, bv, q, k, v);

    node_vec<<<NN*LD/64, 256, 0, stream>>>(vec_bf, wvecT, vdot, vec3, Vt, Vs);

    edge_attn<<<NE/64, 256, 0, stream>>>(ef_bf, wdkT, bdk, wdvT, bdv, snd, rcv, dist,
                                         q, k, v, vj);

    edge_df<<<dim3(NE/32, 4), 256, 0, stream>>>(ef, Wf, bf_, eidx, snd, rcv, dij, Vt, Vs, df);

    edge_s<<<NE/64, 256, 0, stream>>>(vj, wsT, bs, s12);

    node_gather<<<NN, 256, 0, stream>>>(offs, eidx, snd, vj, s12, dij, vec_bf,
                                        Wo, bo, vdot, vec3, dx, dvec);
}